// Round 3
// baseline (228.657 us; speedup 1.0000x reference)
//
#include <hip/hip_runtime.h>
#include <cmath>

// ---------------------------------------------------------------------------
// Problem constants (from reference)
// ---------------------------------------------------------------------------
constexpr int kNsh    = 9;      // (LMAX+1)^2, LMAX=2
constexpr int kF      = 64;
constexpr int kNrbf   = 20;
constexpr int kNAtoms = 1000;
constexpr int kNPairs = 10000;
constexpr float kCutoffF = 5.0f;
constexpr int kMaxNZ  = 200;

// ---------------------------------------------------------------------------
// Compile-time real Clebsch-Gordan table (mirrors the reference _real_cg)
// ---------------------------------------------------------------------------
struct CGSparse {
  int n;
  int c[kMaxNZ];
  int a[kMaxNZ];
  int b[kMaxNZ];
  float v[kMaxNZ];
};

constexpr double cfact(int n) {
  double r = 1.0;
  for (int i = 2; i <= n; i++) r *= (double)i;
  return r;
}
constexpr double cabs_(double x) { return x < 0 ? -x : x; }
constexpr double csqrt_(double x) {
  if (x <= 0.0) return 0.0;
  double g = x < 1.0 ? 1.0 : x;
  for (int i = 0; i < 60; i++) g = 0.5 * (g + x / g);
  return g;
}

constexpr double cg_cplx(int l1, int m1, int l2, int m2, int l3, int m3) {
  if (m3 != m1 + m2) return 0.0;
  int lo = l1 > l2 ? l1 - l2 : l2 - l1;
  if (l3 < lo || l3 > l1 + l2) return 0.0;
  double pre = csqrt_((2 * l3 + 1) * cfact(l3 + l1 - l2) * cfact(l3 - l1 + l2) *
                      cfact(l1 + l2 - l3) / cfact(l1 + l2 + l3 + 1));
  pre *= csqrt_(cfact(l3 + m3) * cfact(l3 - m3) * cfact(l1 - m1) *
                cfact(l1 + m1) * cfact(l2 - m2) * cfact(l2 + m2));
  double s = 0.0;
  for (int k = 0; k <= l1 + l2 - l3; k++) {
    int d0 = k, d1 = l1 + l2 - l3 - k, d2 = l1 - m1 - k;
    int d3 = l2 + m2 - k, d4 = l3 - l2 + m1 + k, d5 = l3 - l1 - m2 + k;
    if (d0 < 0 || d1 < 0 || d2 < 0 || d3 < 0 || d4 < 0 || d5 < 0) continue;
    double den = cfact(d0) * cfact(d1) * cfact(d2) * cfact(d3) * cfact(d4) * cfact(d5);
    s += ((k % 2) ? -1.0 : 1.0) / den;
  }
  return pre * s;
}

constexpr CGSparse build_cg() {
  CGSparse out{};
  int lidx[9] = {0, 1, 1, 1, 2, 2, 2, 2, 2};
  int midx[9] = {0, -1, 0, 1, -2, -1, 0, 1, 2};
  double Ur[9][9] = {};
  double Ui[9][9] = {};
  for (int l = 0; l <= 2; l++) {
    int base = l * l + l;
    Ur[base][base] = 1.0;
    for (int m = 1; m <= l; m++) {
      double s2 = 1.0 / csqrt_(2.0);
      double sgn = (m % 2) ? -1.0 : 1.0;
      Ur[base + m][base - m] = s2;
      Ur[base + m][base + m] = sgn * s2;
      Ui[base - m][base - m] = s2;
      Ui[base - m][base + m] = -sgn * s2;
    }
  }
  double cgr[9][9][9] = {};
  for (int i = 0; i < 9; i++)
    for (int j = 0; j < 9; j++)
      for (int k = 0; k < 9; k++) {
        double cv = cg_cplx(lidx[i], midx[i], lidx[j], midx[j], lidx[k], midx[k]);
        if (cv == 0.0) continue;
        for (int a2 = 0; a2 < 9; a2++) {
          if (Ur[a2][i] == 0.0 && Ui[a2][i] == 0.0) continue;
          for (int b2 = 0; b2 < 9; b2++) {
            if (Ur[b2][j] == 0.0 && Ui[b2][j] == 0.0) continue;
            for (int c2 = 0; c2 < 9; c2++) {
              if (Ur[c2][k] == 0.0 && Ui[c2][k] == 0.0) continue;
              double ar = Ur[a2][i], ai = Ui[a2][i];
              double br = Ur[b2][j], bi = Ui[b2][j];
              double cr = Ur[c2][k], ci = -Ui[c2][k];  // conj
              double pr = ar * br - ai * bi;
              double pi = ar * bi + ai * br;
              double rr = pr * cr - pi * ci;  // real part
              cgr[c2][a2][b2] += rr * cv;
            }
          }
        }
      }
  int n = 0;
  for (int c2 = 0; c2 < 9; c2++)
    for (int a2 = 0; a2 < 9; a2++)
      for (int b2 = 0; b2 < 9; b2++) {
        bool mask = ((lidx[a2] + lidx[b2]) % 2) == (lidx[c2] % 2);
        double v = mask ? cgr[c2][a2][b2] : 0.0;
        if (cabs_(v) > 1e-9) {
          out.c[n] = c2;
          out.a[n] = a2;
          out.b[n] = b2;
          out.v[n] = (float)v;
          n++;
        }
      }
  out.n = n;
  return out;
}

constexpr CGSparse CG = build_cg();
static_assert(CG.n > 0 && CG.n <= kMaxNZ, "CG table size out of range");

// ---------------------------------------------------------------------------
// Grid partition for the fused pre-kernel
// ---------------------------------------------------------------------------
constexpr int kPreBlkPairs = kNPairs / 4;                       // 2500
constexpr int kPreBlkInit  = (kNAtoms * kNsh * kF + 255) / 256; // 2250
constexpr int kPreBlkSeg   = (kNAtoms + 1 + 255) / 256;         // 4
constexpr int kPreBlkTotal = kPreBlkPairs + kPreBlkInit + kPreBlkSeg;

// ---------------------------------------------------------------------------
// Fused pre-kernel: pair geometry+filters | x init | segment offsets
// ---------------------------------------------------------------------------
__global__ __launch_bounds__(256) void k_pre(
    const float* __restrict__ rij, const float* __restrict__ Wf,
    const float* __restrict__ bf, const int* __restrict__ Z,
    const float* __restrict__ emb, const int* __restrict__ idx_i,
    float* __restrict__ Ypd, float* __restrict__ Wpair,
    float* __restrict__ x0, int* __restrict__ seg) {
  const int blk = blockIdx.x;
  if (blk < kPreBlkPairs) {
    // ---- per-pair geometry + radial filters (one wave per pair) ----
    int wv = threadIdx.x >> 6;
    int f = threadIdx.x & 63;
    int p = blk * 4 + wv;
    float rx = rij[3 * p + 0], ry = rij[3 * p + 1], rz = rij[3 * p + 2];
    float d = sqrtf(rx * rx + ry * ry + rz * rz);
    float inv = 1.0f / d;
    float x = rx * inv, y = ry * inv, z = rz * inv;
    const float c0 = 0.28209479177387814f;  // 0.5/sqrt(pi)
    const float c1 = 0.4886025119029199f;   // sqrt(3/(4pi))
    const float c2 = 1.0925484305920792f;   // 0.5*sqrt(15/pi)
    const float c3 = 0.31539156525252005f;  // 0.25*sqrt(5/pi)
    const float c4 = 0.5462742152960396f;   // 0.25*sqrt(15/pi)
    if (f < 9) {
      float yv =
          (f == 0) ? c0 :
          (f == 1) ? c1 * y :
          (f == 2) ? c1 * z :
          (f == 3) ? c1 * x :
          (f == 4) ? c2 * x * y :
          (f == 5) ? c2 * y * z :
          (f == 6) ? c3 * (3.0f * z * z - 1.0f) :
          (f == 7) ? c2 * x * z :
                     c4 * (x * x - y * y);
      Ypd[p * 16 + f] = yv;
    }
    float cut = (d < kCutoffF) ? 0.5f * (cosf(d * (float)(M_PI / 5.0)) + 1.0f) : 0.0f;
    float radial[kNrbf];
    const float width = kCutoffF / (kNrbf - 1);
    const float coef = -0.5f / (width * width);
    #pragma unroll
    for (int k = 0; k < kNrbf; k++) {
      float off = (kCutoffF * k) / (kNrbf - 1);
      float tt = d - off;
      radial[k] = expf(coef * tt * tt);
    }
    #pragma unroll
    for (int t = 0; t < 2; t++) {
      #pragma unroll
      for (int l = 0; l < 3; l++) {
        float w = bf[t * 192 + l * 64 + f];
        #pragma unroll
        for (int k = 0; k < kNrbf; k++) {
          w += radial[k] * Wf[t * (kNrbf * 192) + k * 192 + l * 64 + f];
        }
        Wpair[t * (kNPairs * 192) + p * 192 + l * 64 + f] = w * cut;
      }
    }
  } else if (blk < kPreBlkPairs + kPreBlkInit) {
    // ---- x0 init ----
    int tid = (blk - kPreBlkPairs) * 256 + threadIdx.x;
    if (tid < kNAtoms * kNsh * kF) {
      int f = tid & 63;
      int c = (tid >> 6) % kNsh;
      int atom = tid / (kNsh * kF);
      float v = 0.0f;
      if (c == 0) v = emb[Z[atom] * kF + f];
      x0[tid] = v;
    }
  } else {
    // ---- segment offsets: seg[a] = lower_bound(idx_i, a) ----
    int a = (blk - kPreBlkPairs - kPreBlkInit) * 256 + threadIdx.x;
    if (a <= kNAtoms) {
      int lo = 0, hi = kNPairs;
      while (lo < hi) {
        int mid = (lo + hi) >> 1;
        if (idx_i[mid] < a) lo = mid + 1; else hi = mid;
      }
      seg[a] = lo;
    }
  }
}

// ---------------------------------------------------------------------------
// Message kernel: one wave per pair -> ypair[p][c][f] (no atomics)
// ---------------------------------------------------------------------------
__global__ __launch_bounds__(256) void k_message(
    const float* __restrict__ x_in, const int* __restrict__ idx_j,
    const float* __restrict__ Ypd, const float* __restrict__ Wpair,
    float* __restrict__ ypair) {
  const int wv = threadIdx.x >> 6;
  const int f = threadIdx.x & 63;
  const int p = blockIdx.x * 4 + wv;
  const float* Yp = Ypd + p * 16;
  const float* Wp = Wpair + p * 192;
  float Wl0 = Wp[f], Wl1 = Wp[64 + f], Wl2 = Wp[128 + f];
  const int j = __builtin_amdgcn_readfirstlane(idx_j[p]);
  const float* xj = x_in + j * (kNsh * kF);
  float xv[9];
  #pragma unroll
  for (int a = 0; a < 9; a++) xv[a] = xj[a * kF + f];
  float YW[9];
  YW[0] = Yp[0] * Wl0;
  YW[1] = Yp[1] * Wl1;
  YW[2] = Yp[2] * Wl1;
  YW[3] = Yp[3] * Wl1;
  #pragma unroll
  for (int b = 4; b < 9; b++) YW[b] = Yp[b] * Wl2;
  float y[9] = {0, 0, 0, 0, 0, 0, 0, 0, 0};
  #pragma unroll
  for (int e = 0; e < CG.n; e++) {
    y[CG.c[e]] += CG.v[e] * YW[CG.b[e]] * xv[CG.a[e]];
  }
  float* yp = ypair + p * (kNsh * kF);
  #pragma unroll
  for (int c = 0; c < 9; c++) yp[c * kF + f] = y[c];
}

// ---------------------------------------------------------------------------
// Update kernel: one block (256 thr = 4 waves) per atom.
//   dx = segment-sum(ypair) ; ddx = dx@W1 ; t2 = dx + CG(dx,ddx) ;
//   dx2 = t2@W2 ; gate ; dx3 = dx2*sig(gate) ; x_out = x_in + dx3@W3
// ---------------------------------------------------------------------------
__global__ __launch_bounds__(256) void k_update(
    const float* __restrict__ ypair, const int* __restrict__ seg,
    const float* __restrict__ x_in, const float* __restrict__ W1,
    const float* __restrict__ W2, const float* __restrict__ W3,
    const float* __restrict__ Wg, const float* __restrict__ bg,
    float* __restrict__ x_out) {
  const int atom = blockIdx.x;
  const int wv = threadIdx.x >> 6;  // 0..3
  const int f = threadIdx.x & 63;

  __shared__ float sA[kF][12];        // f-major staging for k-loop broadcasts
  __shared__ float sP[4][kNsh][kF];   // wave partials / c-major staging

  // ---------------- segment aggregation (4-way pair split) ----------------
  float y[9] = {0, 0, 0, 0, 0, 0, 0, 0, 0};
  const int s0 = seg[atom], s1 = seg[atom + 1];
  for (int p = s0 + wv; p < s1; p += 4) {
    const float* yp = ypair + p * (kNsh * kF);
    #pragma unroll
    for (int c = 0; c < 9; c++) y[c] += yp[c * kF + f];
  }
  #pragma unroll
  for (int c = 0; c < 9; c++) sP[wv][c][f] = y[c];
  __syncthreads();  // 1
  float dxv[9];
  #pragma unroll
  for (int c = 0; c < 9; c++) {
    dxv[c] = sP[0][c][f] + sP[1][c][f] + sP[2][c][f] + sP[3][c][f];
  }
  if (wv == 0) {
    #pragma unroll
    for (int c = 0; c < 9; c++) sA[f][c] = dxv[c];
  }
  __syncthreads();  // 2

  // channel split across waves: {0-1, 2-3, 4-5, 6-8}
  const int c_base = (wv < 3) ? wv * 2 : 6;
  const int c_cnt = (wv < 3) ? 2 : 3;

  // ---------------- matmul1: ddx = dx @ W1 ----------------
  float acc[3] = {0, 0, 0};
  for (int k = 0; k < kF; k++) {
    float w = W1[k * kF + f];
    #pragma unroll
    for (int i = 0; i < 3; i++) {
      if (i < c_cnt) acc[i] += sA[k][c_base + i] * w;
    }
  }
  #pragma unroll
  for (int i = 0; i < 3; i++) {
    if (i < c_cnt) sP[0][c_base + i][f] = acc[i];
  }
  __syncthreads();  // 3

  // ---------------- tp + t2 ----------------
  float ddx[9];
  #pragma unroll
  for (int c = 0; c < 9; c++) ddx[c] = sP[0][c][f];
  float t2[9];
  #pragma unroll
  for (int c = 0; c < 9; c++) t2[c] = dxv[c];
  #pragma unroll
  for (int e = 0; e < CG.n; e++) {
    t2[CG.c[e]] += CG.v[e] * dxv[CG.a[e]] * ddx[CG.b[e]];
  }
  if (wv == 0) {
    #pragma unroll
    for (int c = 0; c < 9; c++) sA[f][c] = t2[c];
  }
  __syncthreads();  // 4

  // ---------------- matmul2: dx2 = t2 @ W2 ----------------
  float acc2[3] = {0, 0, 0};
  for (int k = 0; k < kF; k++) {
    float w = W2[k * kF + f];
    #pragma unroll
    for (int i = 0; i < 3; i++) {
      if (i < c_cnt) acc2[i] += sA[k][c_base + i] * w;
    }
  }
  #pragma unroll
  for (int i = 0; i < 3; i++) {
    if (i < c_cnt) sP[1][c_base + i][f] = acc2[i];
  }
  __syncthreads();  // 5

  // ---------------- gate + dx3 staging ----------------
  if (wv == 0) {
    float g0 = bg[f], g1 = bg[64 + f], g2 = bg[128 + f];
    for (int k = 0; k < kF; k++) {
      float v0 = sP[1][0][k];
      g0 += v0 * Wg[k * 192 + f];
      g1 += v0 * Wg[k * 192 + 64 + f];
      g2 += v0 * Wg[k * 192 + 128 + f];
    }
    g0 = 1.0f / (1.0f + expf(-g0));
    g1 = 1.0f / (1.0f + expf(-g1));
    g2 = 1.0f / (1.0f + expf(-g2));
    float dx2v[9];
    #pragma unroll
    for (int c = 0; c < 9; c++) dx2v[c] = sP[1][c][f];
    sA[f][0] = dx2v[0] * g0;
    sA[f][1] = dx2v[1] * g1;
    sA[f][2] = dx2v[2] * g1;
    sA[f][3] = dx2v[3] * g1;
    #pragma unroll
    for (int c = 4; c < 9; c++) sA[f][c] = dx2v[c] * g2;
  }
  __syncthreads();  // 6

  // ---------------- matmul3 + residual output ----------------
  float acc3[3] = {0, 0, 0};
  for (int k = 0; k < kF; k++) {
    float w = W3[k * kF + f];
    #pragma unroll
    for (int i = 0; i < 3; i++) {
      if (i < c_cnt) acc3[i] += sA[k][c_base + i] * w;
    }
  }
  #pragma unroll
  for (int i = 0; i < 3; i++) {
    if (i < c_cnt) {
      int off = atom * (kNsh * kF) + (c_base + i) * kF + f;
      x_out[off] = x_in[off] + acc3[i];
    }
  }
}

// ---------------------------------------------------------------------------
// Launch
// ---------------------------------------------------------------------------
extern "C" void kernel_launch(void* const* d_in, const int* in_sizes, int n_in,
                              void* d_out, int out_size, void* d_ws, size_t ws_size,
                              hipStream_t stream) {
  const int* Z        = (const int*)d_in[0];
  const float* rij    = (const float*)d_in[1];
  const int* idx_i    = (const int*)d_in[2];
  const int* idx_j    = (const int*)d_in[3];
  const float* emb    = (const float*)d_in[4];
  const float* Wf     = (const float*)d_in[5];
  const float* bf     = (const float*)d_in[6];
  const float* W1     = (const float*)d_in[7];
  const float* W2     = (const float*)d_in[8];
  const float* W3     = (const float*)d_in[9];
  const float* Wg     = (const float*)d_in[10];
  const float* bg     = (const float*)d_in[11];
  float* x_final = (float*)d_out;

  float* x0    = (float*)d_ws;                       // 576,000
  float* x1    = x0 + kNAtoms * kNsh * kF;           // 576,000
  float* Ypd   = x1 + kNAtoms * kNsh * kF;           // 160,000
  float* Wpair = Ypd + kNPairs * 16;                 // 3,840,000
  float* ypair = Wpair + 2 * kNPairs * 192;          // 5,760,000
  int*   seg   = (int*)(ypair + kNPairs * kNsh * kF);

  k_pre<<<kPreBlkTotal, 256, 0, stream>>>(
      rij, Wf, bf, Z, emb, idx_i, Ypd, Wpair, x0, seg);

  // t = 0: x0 -> x1
  k_message<<<kNPairs / 4, 256, 0, stream>>>(x0, idx_j, Ypd, Wpair, ypair);
  k_update<<<kNAtoms, 256, 0, stream>>>(
      ypair, seg, x0, W1, W2, W3, Wg, bg, x1);

  // t = 1: x1 -> d_out
  k_message<<<kNPairs / 4, 256, 0, stream>>>(
      x1, idx_j, Ypd, Wpair + kNPairs * 192, ypair);
  k_update<<<kNAtoms, 256, 0, stream>>>(
      ypair, seg, x1, W1 + kF * kF, W2 + kF * kF, W3 + kF * kF,
      Wg + kF * 192, bg + 192, x_final);
}

// Round 4
// 164.314 us; speedup vs baseline: 1.3916x; 1.3916x over previous
//
#include <hip/hip_runtime.h>
#include <cmath>

// ---------------------------------------------------------------------------
// Problem constants (from reference)
// ---------------------------------------------------------------------------
constexpr int kNsh    = 9;      // (LMAX+1)^2, LMAX=2
constexpr int kF      = 64;
constexpr int kNrbf   = 20;
constexpr int kNAtoms = 1000;
constexpr int kNPairs = 10000;
constexpr float kCutoffF = 5.0f;
constexpr int kMaxNZ  = 200;

// ---------------------------------------------------------------------------
// Compile-time real Clebsch-Gordan table (mirrors the reference _real_cg)
// ---------------------------------------------------------------------------
struct CGSparse {
  int n;
  int c[kMaxNZ];
  int a[kMaxNZ];
  int b[kMaxNZ];
  float v[kMaxNZ];
};

constexpr double cfact(int n) {
  double r = 1.0;
  for (int i = 2; i <= n; i++) r *= (double)i;
  return r;
}
constexpr double cabs_(double x) { return x < 0 ? -x : x; }
constexpr double csqrt_(double x) {
  if (x <= 0.0) return 0.0;
  double g = x < 1.0 ? 1.0 : x;
  for (int i = 0; i < 60; i++) g = 0.5 * (g + x / g);
  return g;
}

constexpr double cg_cplx(int l1, int m1, int l2, int m2, int l3, int m3) {
  if (m3 != m1 + m2) return 0.0;
  int lo = l1 > l2 ? l1 - l2 : l2 - l1;
  if (l3 < lo || l3 > l1 + l2) return 0.0;
  double pre = csqrt_((2 * l3 + 1) * cfact(l3 + l1 - l2) * cfact(l3 - l1 + l2) *
                      cfact(l1 + l2 - l3) / cfact(l1 + l2 + l3 + 1));
  pre *= csqrt_(cfact(l3 + m3) * cfact(l3 - m3) * cfact(l1 - m1) *
                cfact(l1 + m1) * cfact(l2 - m2) * cfact(l2 + m2));
  double s = 0.0;
  for (int k = 0; k <= l1 + l2 - l3; k++) {
    int d0 = k, d1 = l1 + l2 - l3 - k, d2 = l1 - m1 - k;
    int d3 = l2 + m2 - k, d4 = l3 - l2 + m1 + k, d5 = l3 - l1 - m2 + k;
    if (d0 < 0 || d1 < 0 || d2 < 0 || d3 < 0 || d4 < 0 || d5 < 0) continue;
    double den = cfact(d0) * cfact(d1) * cfact(d2) * cfact(d3) * cfact(d4) * cfact(d5);
    s += ((k % 2) ? -1.0 : 1.0) / den;
  }
  return pre * s;
}

constexpr CGSparse build_cg() {
  CGSparse out{};
  int lidx[9] = {0, 1, 1, 1, 2, 2, 2, 2, 2};
  int midx[9] = {0, -1, 0, 1, -2, -1, 0, 1, 2};
  double Ur[9][9] = {};
  double Ui[9][9] = {};
  for (int l = 0; l <= 2; l++) {
    int base = l * l + l;
    Ur[base][base] = 1.0;
    for (int m = 1; m <= l; m++) {
      double s2 = 1.0 / csqrt_(2.0);
      double sgn = (m % 2) ? -1.0 : 1.0;
      Ur[base + m][base - m] = s2;
      Ur[base + m][base + m] = sgn * s2;
      Ui[base - m][base - m] = s2;
      Ui[base - m][base + m] = -sgn * s2;
    }
  }
  double cgr[9][9][9] = {};
  for (int i = 0; i < 9; i++)
    for (int j = 0; j < 9; j++)
      for (int k = 0; k < 9; k++) {
        double cv = cg_cplx(lidx[i], midx[i], lidx[j], midx[j], lidx[k], midx[k]);
        if (cv == 0.0) continue;
        for (int a2 = 0; a2 < 9; a2++) {
          if (Ur[a2][i] == 0.0 && Ui[a2][i] == 0.0) continue;
          for (int b2 = 0; b2 < 9; b2++) {
            if (Ur[b2][j] == 0.0 && Ui[b2][j] == 0.0) continue;
            for (int c2 = 0; c2 < 9; c2++) {
              if (Ur[c2][k] == 0.0 && Ui[c2][k] == 0.0) continue;
              double ar = Ur[a2][i], ai = Ui[a2][i];
              double br = Ur[b2][j], bi = Ui[b2][j];
              double cr = Ur[c2][k], ci = -Ui[c2][k];  // conj
              double pr = ar * br - ai * bi;
              double pi = ar * bi + ai * br;
              double rr = pr * cr - pi * ci;  // real part
              cgr[c2][a2][b2] += rr * cv;
            }
          }
        }
      }
  int n = 0;
  for (int c2 = 0; c2 < 9; c2++)
    for (int a2 = 0; a2 < 9; a2++)
      for (int b2 = 0; b2 < 9; b2++) {
        bool mask = ((lidx[a2] + lidx[b2]) % 2) == (lidx[c2] % 2);
        double v = mask ? cgr[c2][a2][b2] : 0.0;
        if (cabs_(v) > 1e-9) {
          out.c[n] = c2;
          out.a[n] = a2;
          out.b[n] = b2;
          out.v[n] = (float)v;
          n++;
        }
      }
  out.n = n;
  return out;
}

constexpr CGSparse CG = build_cg();
static_assert(CG.n > 0 && CG.n <= kMaxNZ, "CG table size out of range");

// ---------------------------------------------------------------------------
// Grid partition for the fused pre-kernel
// ---------------------------------------------------------------------------
constexpr int kPreBlkPairs = kNPairs / 4;                       // 2500
constexpr int kPreBlkInit  = (kNAtoms * kNsh * kF + 255) / 256; // 2250
constexpr int kPreBlkSeg   = (kNAtoms + 1 + 255) / 256;         // 4
constexpr int kPreBlkTotal = kPreBlkPairs + kPreBlkInit + kPreBlkSeg;

// ---------------------------------------------------------------------------
// Fused pre-kernel: pair geometry+filters | x init | segment offsets
// ---------------------------------------------------------------------------
__global__ __launch_bounds__(256) void k_pre(
    const float* __restrict__ rij, const float* __restrict__ Wf,
    const float* __restrict__ bf, const int* __restrict__ Z,
    const float* __restrict__ emb, const int* __restrict__ idx_i,
    float* __restrict__ Ypd, float* __restrict__ Wpair,
    float* __restrict__ x0, int* __restrict__ seg) {
  const int blk = blockIdx.x;
  if (blk < kPreBlkPairs) {
    // ---- per-pair geometry + radial filters (one wave per pair) ----
    int wv = threadIdx.x >> 6;
    int f = threadIdx.x & 63;
    int p = blk * 4 + wv;
    float rx = rij[3 * p + 0], ry = rij[3 * p + 1], rz = rij[3 * p + 2];
    float d = sqrtf(rx * rx + ry * ry + rz * rz);
    float inv = 1.0f / d;
    float x = rx * inv, y = ry * inv, z = rz * inv;
    const float c0 = 0.28209479177387814f;  // 0.5/sqrt(pi)
    const float c1 = 0.4886025119029199f;   // sqrt(3/(4pi))
    const float c2 = 1.0925484305920792f;   // 0.5*sqrt(15/pi)
    const float c3 = 0.31539156525252005f;  // 0.25*sqrt(5/pi)
    const float c4 = 0.5462742152960396f;   // 0.25*sqrt(15/pi)
    if (f < 9) {
      float yv =
          (f == 0) ? c0 :
          (f == 1) ? c1 * y :
          (f == 2) ? c1 * z :
          (f == 3) ? c1 * x :
          (f == 4) ? c2 * x * y :
          (f == 5) ? c2 * y * z :
          (f == 6) ? c3 * (3.0f * z * z - 1.0f) :
          (f == 7) ? c2 * x * z :
                     c4 * (x * x - y * y);
      Ypd[p * 16 + f] = yv;
    }
    float cut = (d < kCutoffF) ? 0.5f * (cosf(d * (float)(M_PI / 5.0)) + 1.0f) : 0.0f;
    float radial[kNrbf];
    const float width = kCutoffF / (kNrbf - 1);
    const float coef = -0.5f / (width * width);
    #pragma unroll
    for (int k = 0; k < kNrbf; k++) {
      float off = (kCutoffF * k) / (kNrbf - 1);
      float tt = d - off;
      radial[k] = expf(coef * tt * tt);
    }
    #pragma unroll
    for (int t = 0; t < 2; t++) {
      #pragma unroll
      for (int l = 0; l < 3; l++) {
        float w = bf[t * 192 + l * 64 + f];
        #pragma unroll
        for (int k = 0; k < kNrbf; k++) {
          w += radial[k] * Wf[t * (kNrbf * 192) + k * 192 + l * 64 + f];
        }
        Wpair[t * (kNPairs * 192) + p * 192 + l * 64 + f] = w * cut;
      }
    }
  } else if (blk < kPreBlkPairs + kPreBlkInit) {
    // ---- x0 init ----
    int tid = (blk - kPreBlkPairs) * 256 + threadIdx.x;
    if (tid < kNAtoms * kNsh * kF) {
      int f = tid & 63;
      int c = (tid >> 6) % kNsh;
      int atom = tid / (kNsh * kF);
      float v = 0.0f;
      if (c == 0) v = emb[Z[atom] * kF + f];
      x0[tid] = v;
    }
  } else {
    // ---- segment offsets: seg[a] = lower_bound(idx_i, a) ----
    int a = (blk - kPreBlkPairs - kPreBlkInit) * 256 + threadIdx.x;
    if (a <= kNAtoms) {
      int lo = 0, hi = kNPairs;
      while (lo < hi) {
        int mid = (lo + hi) >> 1;
        if (idx_i[mid] < a) lo = mid + 1; else hi = mid;
      }
      seg[a] = lo;
    }
  }
}

// ---------------------------------------------------------------------------
// Message kernel: one wave per pair -> ypair[p][c][f] (no atomics)
// ---------------------------------------------------------------------------
__global__ __launch_bounds__(256) void k_message(
    const float* __restrict__ x_in, const int* __restrict__ idx_j,
    const float* __restrict__ Ypd, const float* __restrict__ Wpair,
    float* __restrict__ ypair) {
  const int wv = threadIdx.x >> 6;
  const int f = threadIdx.x & 63;
  const int p = blockIdx.x * 4 + wv;
  const float* Yp = Ypd + p * 16;
  const float* Wp = Wpair + p * 192;
  float Wl0 = Wp[f], Wl1 = Wp[64 + f], Wl2 = Wp[128 + f];
  const int j = __builtin_amdgcn_readfirstlane(idx_j[p]);
  const float* xj = x_in + j * (kNsh * kF);
  float xv[9];
  #pragma unroll
  for (int a = 0; a < 9; a++) xv[a] = xj[a * kF + f];
  float YW[9];
  YW[0] = Yp[0] * Wl0;
  YW[1] = Yp[1] * Wl1;
  YW[2] = Yp[2] * Wl1;
  YW[3] = Yp[3] * Wl1;
  #pragma unroll
  for (int b = 4; b < 9; b++) YW[b] = Yp[b] * Wl2;
  float y[9] = {0, 0, 0, 0, 0, 0, 0, 0, 0};
  #pragma unroll
  for (int e = 0; e < CG.n; e++) {
    y[CG.c[e]] += CG.v[e] * YW[CG.b[e]] * xv[CG.a[e]];
  }
  float* yp = ypair + p * (kNsh * kF);
  #pragma unroll
  for (int c = 0; c < 9; c++) yp[c * kF + f] = y[c];
}

// ---------------------------------------------------------------------------
// Update kernel: one block (256 thr = 4 waves) per atom.
// All matmul k-loops read LDS only: weights staged per-phase into sW during
// the preceding phase's window (no extra barriers). k-loops unrolled x16.
// ---------------------------------------------------------------------------
__global__ __launch_bounds__(256) void k_update(
    const float* __restrict__ ypair, const int* __restrict__ seg,
    const float* __restrict__ x_in, const float* __restrict__ W1,
    const float* __restrict__ W2, const float* __restrict__ W3,
    const float* __restrict__ Wg, const float* __restrict__ bg,
    float* __restrict__ x_out) {
  const int atom = blockIdx.x;
  const int tid = threadIdx.x;
  const int wv = tid >> 6;  // 0..3
  const int f = tid & 63;

  __shared__ float sA[kF][13];        // f-major staging (stride 13: bank-clean)
  __shared__ float sP[4][kNsh][kF];   // wave partials / c-major staging
  __shared__ float sW[kF * kF];       // staged weight matrix for current phase

  // ---------------- segment aggregation (4-way pair split) ----------------
  float y[9] = {0, 0, 0, 0, 0, 0, 0, 0, 0};
  const int s0 = seg[atom], s1 = seg[atom + 1];
  #pragma unroll 2
  for (int p = s0 + wv; p < s1; p += 4) {
    const float* yp = ypair + p * (kNsh * kF);
    #pragma unroll
    for (int c = 0; c < 9; c++) y[c] += yp[c * kF + f];
  }
  #pragma unroll
  for (int c = 0; c < 9; c++) sP[wv][c][f] = y[c];
  __syncthreads();  // 1
  float dxv[9];
  #pragma unroll
  for (int c = 0; c < 9; c++) {
    dxv[c] = sP[0][c][f] + sP[1][c][f] + sP[2][c][f] + sP[3][c][f];
  }
  if (wv == 0) {
    #pragma unroll
    for (int c = 0; c < 9; c++) sA[f][c] = dxv[c];
  }
  // stage W1 into sW (coalesced float4)
  {
    const float4* W4 = (const float4*)W1;
    float4* s4 = (float4*)sW;
    #pragma unroll
    for (int r = 0; r < 4; r++) s4[r * 256 + tid] = W4[r * 256 + tid];
  }
  __syncthreads();  // 2

  // channel split across waves: {0-1, 2-3, 4-5, 6-8}
  const int c_base = (wv < 3) ? wv * 2 : 6;
  const int c_cnt = (wv < 3) ? 2 : 3;

  // ---------------- matmul1: ddx = dx @ W1 (LDS x LDS) ----------------
  float acc[3] = {0, 0, 0};
  #pragma unroll 16
  for (int k = 0; k < kF; k++) {
    float w = sW[k * kF + f];
    #pragma unroll
    for (int i = 0; i < 3; i++) {
      if (i < c_cnt) acc[i] += sA[k][c_base + i] * w;
    }
  }
  #pragma unroll
  for (int i = 0; i < 3; i++) {
    if (i < c_cnt) sP[0][c_base + i][f] = acc[i];
  }
  __syncthreads();  // 3

  // ---------------- tp + t2 ; stage sA=t2 and sW=W2 ----------------
  float ddx[9];
  #pragma unroll
  for (int c = 0; c < 9; c++) ddx[c] = sP[0][c][f];
  float t2[9];
  #pragma unroll
  for (int c = 0; c < 9; c++) t2[c] = dxv[c];
  #pragma unroll
  for (int e = 0; e < CG.n; e++) {
    t2[CG.c[e]] += CG.v[e] * dxv[CG.a[e]] * ddx[CG.b[e]];
  }
  if (wv == 0) {
    #pragma unroll
    for (int c = 0; c < 9; c++) sA[f][c] = t2[c];
  }
  {
    const float4* W4 = (const float4*)W2;
    float4* s4 = (float4*)sW;
    #pragma unroll
    for (int r = 0; r < 4; r++) s4[r * 256 + tid] = W4[r * 256 + tid];
  }
  __syncthreads();  // 4

  // ---------------- matmul2: dx2 = t2 @ W2 ----------------
  float acc2[3] = {0, 0, 0};
  #pragma unroll 16
  for (int k = 0; k < kF; k++) {
    float w = sW[k * kF + f];
    #pragma unroll
    for (int i = 0; i < 3; i++) {
      if (i < c_cnt) acc2[i] += sA[k][c_base + i] * w;
    }
  }
  #pragma unroll
  for (int i = 0; i < 3; i++) {
    if (i < c_cnt) sP[1][c_base + i][f] = acc2[i];
  }
  __syncthreads();  // 5

  // ---------------- gate (all waves, redundant) ; stage dx3, W3 ----------
  float g0 = bg[f], g1 = bg[64 + f], g2 = bg[128 + f];
  #pragma unroll 8
  for (int k = 0; k < kF; k++) {
    float v0 = sP[1][0][k];
    g0 += v0 * Wg[k * 192 + f];
    g1 += v0 * Wg[k * 192 + 64 + f];
    g2 += v0 * Wg[k * 192 + 128 + f];
  }
  g0 = 1.0f / (1.0f + expf(-g0));
  g1 = 1.0f / (1.0f + expf(-g1));
  g2 = 1.0f / (1.0f + expf(-g2));
  if (wv == 0) {
    float dx2v[9];
    #pragma unroll
    for (int c = 0; c < 9; c++) dx2v[c] = sP[1][c][f];
    sA[f][0] = dx2v[0] * g0;
    sA[f][1] = dx2v[1] * g1;
    sA[f][2] = dx2v[2] * g1;
    sA[f][3] = dx2v[3] * g1;
    #pragma unroll
    for (int c = 4; c < 9; c++) sA[f][c] = dx2v[c] * g2;
  }
  {
    const float4* W4 = (const float4*)W3;
    float4* s4 = (float4*)sW;
    #pragma unroll
    for (int r = 0; r < 4; r++) s4[r * 256 + tid] = W4[r * 256 + tid];
  }
  __syncthreads();  // 6

  // ---------------- matmul3 + residual output ----------------
  float acc3[3] = {0, 0, 0};
  #pragma unroll 16
  for (int k = 0; k < kF; k++) {
    float w = sW[k * kF + f];
    #pragma unroll
    for (int i = 0; i < 3; i++) {
      if (i < c_cnt) acc3[i] += sA[k][c_base + i] * w;
    }
  }
  #pragma unroll
  for (int i = 0; i < 3; i++) {
    if (i < c_cnt) {
      int off = atom * (kNsh * kF) + (c_base + i) * kF + f;
      x_out[off] = x_in[off] + acc3[i];
    }
  }
}

// ---------------------------------------------------------------------------
// Launch
// ---------------------------------------------------------------------------
extern "C" void kernel_launch(void* const* d_in, const int* in_sizes, int n_in,
                              void* d_out, int out_size, void* d_ws, size_t ws_size,
                              hipStream_t stream) {
  const int* Z        = (const int*)d_in[0];
  const float* rij    = (const float*)d_in[1];
  const int* idx_i    = (const int*)d_in[2];
  const int* idx_j    = (const int*)d_in[3];
  const float* emb    = (const float*)d_in[4];
  const float* Wf     = (const float*)d_in[5];
  const float* bf     = (const float*)d_in[6];
  const float* W1     = (const float*)d_in[7];
  const float* W2     = (const float*)d_in[8];
  const float* W3     = (const float*)d_in[9];
  const float* Wg     = (const float*)d_in[10];
  const float* bg     = (const float*)d_in[11];
  float* x_final = (float*)d_out;

  float* x0    = (float*)d_ws;                       // 576,000
  float* x1    = x0 + kNAtoms * kNsh * kF;           // 576,000
  float* Ypd   = x1 + kNAtoms * kNsh * kF;           // 160,000
  float* Wpair = Ypd + kNPairs * 16;                 // 3,840,000
  float* ypair = Wpair + 2 * kNPairs * 192;          // 5,760,000
  int*   seg   = (int*)(ypair + kNPairs * kNsh * kF);

  k_pre<<<kPreBlkTotal, 256, 0, stream>>>(
      rij, Wf, bf, Z, emb, idx_i, Ypd, Wpair, x0, seg);

  // t = 0: x0 -> x1
  k_message<<<kNPairs / 4, 256, 0, stream>>>(x0, idx_j, Ypd, Wpair, ypair);
  k_update<<<kNAtoms, 256, 0, stream>>>(
      ypair, seg, x0, W1, W2, W3, Wg, bg, x1);

  // t = 1: x1 -> d_out
  k_message<<<kNPairs / 4, 256, 0, stream>>>(
      x1, idx_j, Ypd, Wpair + kNPairs * 192, ypair);
  k_update<<<kNAtoms, 256, 0, stream>>>(
      ypair, seg, x1, W1 + kF * kF, W2 + kF * kF, W3 + kF * kF,
      Wg + kF * 192, bg + 192, x_final);
}

// Round 5
// 162.715 us; speedup vs baseline: 1.4053x; 1.0098x over previous
//
#include <hip/hip_runtime.h>
#include <cmath>

// ---------------------------------------------------------------------------
// Problem constants (from reference)
// ---------------------------------------------------------------------------
constexpr int kNsh    = 9;      // (LMAX+1)^2, LMAX=2
constexpr int kF      = 64;
constexpr int kNrbf   = 20;
constexpr int kNAtoms = 1000;
constexpr int kNPairs = 10000;
constexpr float kCutoffF = 5.0f;
constexpr int kMaxNZ  = 200;
constexpr int kCp     = 12;         // channel dim padded (9 -> 12) for b128
constexpr int kXs     = kF * kCp;   // 768 floats per atom/pair, internal layout

// ---------------------------------------------------------------------------
// Compile-time real Clebsch-Gordan table (mirrors the reference _real_cg)
// ---------------------------------------------------------------------------
struct CGSparse {
  int n;
  int c[kMaxNZ];
  int a[kMaxNZ];
  int b[kMaxNZ];
  float v[kMaxNZ];
};

constexpr double cfact(int n) {
  double r = 1.0;
  for (int i = 2; i <= n; i++) r *= (double)i;
  return r;
}
constexpr double cabs_(double x) { return x < 0 ? -x : x; }
constexpr double csqrt_(double x) {
  if (x <= 0.0) return 0.0;
  double g = x < 1.0 ? 1.0 : x;
  for (int i = 0; i < 60; i++) g = 0.5 * (g + x / g);
  return g;
}

constexpr double cg_cplx(int l1, int m1, int l2, int m2, int l3, int m3) {
  if (m3 != m1 + m2) return 0.0;
  int lo = l1 > l2 ? l1 - l2 : l2 - l1;
  if (l3 < lo || l3 > l1 + l2) return 0.0;
  double pre = csqrt_((2 * l3 + 1) * cfact(l3 + l1 - l2) * cfact(l3 - l1 + l2) *
                      cfact(l1 + l2 - l3) / cfact(l1 + l2 + l3 + 1));
  pre *= csqrt_(cfact(l3 + m3) * cfact(l3 - m3) * cfact(l1 - m1) *
                cfact(l1 + m1) * cfact(l2 - m2) * cfact(l2 + m2));
  double s = 0.0;
  for (int k = 0; k <= l1 + l2 - l3; k++) {
    int d0 = k, d1 = l1 + l2 - l3 - k, d2 = l1 - m1 - k;
    int d3 = l2 + m2 - k, d4 = l3 - l2 + m1 + k, d5 = l3 - l1 - m2 + k;
    if (d0 < 0 || d1 < 0 || d2 < 0 || d3 < 0 || d4 < 0 || d5 < 0) continue;
    double den = cfact(d0) * cfact(d1) * cfact(d2) * cfact(d3) * cfact(d4) * cfact(d5);
    s += ((k % 2) ? -1.0 : 1.0) / den;
  }
  return pre * s;
}

constexpr CGSparse build_cg() {
  CGSparse out{};
  int lidx[9] = {0, 1, 1, 1, 2, 2, 2, 2, 2};
  int midx[9] = {0, -1, 0, 1, -2, -1, 0, 1, 2};
  double Ur[9][9] = {};
  double Ui[9][9] = {};
  for (int l = 0; l <= 2; l++) {
    int base = l * l + l;
    Ur[base][base] = 1.0;
    for (int m = 1; m <= l; m++) {
      double s2 = 1.0 / csqrt_(2.0);
      double sgn = (m % 2) ? -1.0 : 1.0;
      Ur[base + m][base - m] = s2;
      Ur[base + m][base + m] = sgn * s2;
      Ui[base - m][base - m] = s2;
      Ui[base - m][base + m] = -sgn * s2;
    }
  }
  double cgr[9][9][9] = {};
  for (int i = 0; i < 9; i++)
    for (int j = 0; j < 9; j++)
      for (int k = 0; k < 9; k++) {
        double cv = cg_cplx(lidx[i], midx[i], lidx[j], midx[j], lidx[k], midx[k]);
        if (cv == 0.0) continue;
        for (int a2 = 0; a2 < 9; a2++) {
          if (Ur[a2][i] == 0.0 && Ui[a2][i] == 0.0) continue;
          for (int b2 = 0; b2 < 9; b2++) {
            if (Ur[b2][j] == 0.0 && Ui[b2][j] == 0.0) continue;
            for (int c2 = 0; c2 < 9; c2++) {
              if (Ur[c2][k] == 0.0 && Ui[c2][k] == 0.0) continue;
              double ar = Ur[a2][i], ai = Ui[a2][i];
              double br = Ur[b2][j], bi = Ui[b2][j];
              double cr = Ur[c2][k], ci = -Ui[c2][k];  // conj
              double pr = ar * br - ai * bi;
              double pi = ar * bi + ai * br;
              double rr = pr * cr - pi * ci;  // real part
              cgr[c2][a2][b2] += rr * cv;
            }
          }
        }
      }
  int n = 0;
  for (int c2 = 0; c2 < 9; c2++)
    for (int a2 = 0; a2 < 9; a2++)
      for (int b2 = 0; b2 < 9; b2++) {
        bool mask = ((lidx[a2] + lidx[b2]) % 2) == (lidx[c2] % 2);
        double v = mask ? cgr[c2][a2][b2] : 0.0;
        if (cabs_(v) > 1e-9) {
          out.c[n] = c2;
          out.a[n] = a2;
          out.b[n] = b2;
          out.v[n] = (float)v;
          n++;
        }
      }
  out.n = n;
  return out;
}

constexpr CGSparse CG = build_cg();
static_assert(CG.n > 0 && CG.n <= kMaxNZ, "CG table size out of range");

// ---------------------------------------------------------------------------
// Grid partition for the fused pre-kernel
// ---------------------------------------------------------------------------
constexpr int kPreBlkPairs = kNPairs / 4;                     // 2500
constexpr int kPreBlkInit  = kNAtoms * kF / 256;              // 250
constexpr int kPreBlkSeg   = (kNAtoms + 1 + 255) / 256;       // 4
constexpr int kPreBlkTotal = kPreBlkPairs + kPreBlkInit + kPreBlkSeg;

// ---------------------------------------------------------------------------
// Fused pre-kernel: pair geometry+filters | x init (internal layout) | seg
// ---------------------------------------------------------------------------
__global__ __launch_bounds__(256) void k_pre(
    const float* __restrict__ rij, const float* __restrict__ Wf,
    const float* __restrict__ bf, const int* __restrict__ Z,
    const float* __restrict__ emb, const int* __restrict__ idx_i,
    float* __restrict__ Ypd, float* __restrict__ Wpair,
    float* __restrict__ x0, int* __restrict__ seg) {
  const int blk = blockIdx.x;
  if (blk < kPreBlkPairs) {
    // ---- per-pair geometry + radial filters (one wave per pair) ----
    int wv = threadIdx.x >> 6;
    int f = threadIdx.x & 63;
    int p = blk * 4 + wv;
    float rx = rij[3 * p + 0], ry = rij[3 * p + 1], rz = rij[3 * p + 2];
    float d = sqrtf(rx * rx + ry * ry + rz * rz);
    float inv = 1.0f / d;
    float x = rx * inv, y = ry * inv, z = rz * inv;
    const float c0 = 0.28209479177387814f;  // 0.5/sqrt(pi)
    const float c1 = 0.4886025119029199f;   // sqrt(3/(4pi))
    const float c2 = 1.0925484305920792f;   // 0.5*sqrt(15/pi)
    const float c3 = 0.31539156525252005f;  // 0.25*sqrt(5/pi)
    const float c4 = 0.5462742152960396f;   // 0.25*sqrt(15/pi)
    if (f < 9) {
      float yv =
          (f == 0) ? c0 :
          (f == 1) ? c1 * y :
          (f == 2) ? c1 * z :
          (f == 3) ? c1 * x :
          (f == 4) ? c2 * x * y :
          (f == 5) ? c2 * y * z :
          (f == 6) ? c3 * (3.0f * z * z - 1.0f) :
          (f == 7) ? c2 * x * z :
                     c4 * (x * x - y * y);
      Ypd[p * 16 + f] = yv;
    }
    float cut = (d < kCutoffF) ? 0.5f * (cosf(d * (float)(M_PI / 5.0)) + 1.0f) : 0.0f;
    float radial[kNrbf];
    const float width = kCutoffF / (kNrbf - 1);
    const float coef = -0.5f / (width * width);
    #pragma unroll
    for (int k = 0; k < kNrbf; k++) {
      float off = (kCutoffF * k) / (kNrbf - 1);
      float tt = d - off;
      radial[k] = expf(coef * tt * tt);
    }
    #pragma unroll
    for (int t = 0; t < 2; t++) {
      #pragma unroll
      for (int l = 0; l < 3; l++) {
        float w = bf[t * 192 + l * 64 + f];
        #pragma unroll
        for (int k = 0; k < kNrbf; k++) {
          w += radial[k] * Wf[t * (kNrbf * 192) + k * 192 + l * 64 + f];
        }
        Wpair[t * (kNPairs * 192) + p * 192 + l * 64 + f] = w * cut;
      }
    }
  } else if (blk < kPreBlkPairs + kPreBlkInit) {
    // ---- x0 init, internal layout [atom][f][12] ----
    int tid = (blk - kPreBlkPairs) * 256 + threadIdx.x;
    int atom = tid >> 6;
    int f = tid & 63;
    float e = emb[Z[atom] * kF + f];
    float4* b = (float4*)(x0 + atom * kXs + f * kCp);
    b[0] = make_float4(e, 0.f, 0.f, 0.f);
    b[1] = make_float4(0.f, 0.f, 0.f, 0.f);
    b[2] = make_float4(0.f, 0.f, 0.f, 0.f);
  } else {
    // ---- segment offsets: seg[a] = lower_bound(idx_i, a) ----
    int a = (blk - kPreBlkPairs - kPreBlkInit) * 256 + threadIdx.x;
    if (a <= kNAtoms) {
      int lo = 0, hi = kNPairs;
      while (lo < hi) {
        int mid = (lo + hi) >> 1;
        if (idx_i[mid] < a) lo = mid + 1; else hi = mid;
      }
      seg[a] = lo;
    }
  }
}

// ---------------------------------------------------------------------------
// Message kernel: one wave per pair -> ypair[p][f][12] (b128 gather + store)
// ---------------------------------------------------------------------------
__global__ __launch_bounds__(256) void k_message(
    const float* __restrict__ x_in, const int* __restrict__ idx_j,
    const float* __restrict__ Ypd, const float* __restrict__ Wpair,
    float* __restrict__ ypair) {
  const int wv = threadIdx.x >> 6;
  const int f = threadIdx.x & 63;
  const int p = blockIdx.x * 4 + wv;
  const float* Yp = Ypd + p * 16;
  const float* Wp = Wpair + p * 192;
  float Wl0 = Wp[f], Wl1 = Wp[64 + f], Wl2 = Wp[128 + f];
  const int j = __builtin_amdgcn_readfirstlane(idx_j[p]);
  const float* xj = x_in + j * kXs + f * kCp;
  float xv[12];
  *(float4*)&xv[0] = *(const float4*)(xj + 0);
  *(float4*)&xv[4] = *(const float4*)(xj + 4);
  *(float4*)&xv[8] = *(const float4*)(xj + 8);
  float YW[9];
  YW[0] = Yp[0] * Wl0;
  YW[1] = Yp[1] * Wl1;
  YW[2] = Yp[2] * Wl1;
  YW[3] = Yp[3] * Wl1;
  #pragma unroll
  for (int b = 4; b < 9; b++) YW[b] = Yp[b] * Wl2;
  float y[12] = {0, 0, 0, 0, 0, 0, 0, 0, 0, 0, 0, 0};
  #pragma unroll
  for (int e = 0; e < CG.n; e++) {
    y[CG.c[e]] += CG.v[e] * YW[CG.b[e]] * xv[CG.a[e]];
  }
  float* yp = ypair + p * kXs + f * kCp;
  *(float4*)(yp + 0) = *(float4*)&y[0];
  *(float4*)(yp + 4) = *(float4*)&y[4];
  *(float4*)(yp + 8) = *(float4*)&y[8];
}

// ---------------------------------------------------------------------------
// Update kernel helpers
// ---------------------------------------------------------------------------
__device__ __forceinline__ void stage_w(const float* __restrict__ W,
                                        float* __restrict__ sW, int tid) {
  const float4* g4 = (const float4*)W;
  float4* s4 = (float4*)sW;
  #pragma unroll
  for (int r = 0; r < 16; r++) s4[r * 64 + tid] = g4[r * 64 + tid];
}

__device__ __forceinline__ void mm_tile(const float* __restrict__ sA,
                                        const float* __restrict__ sW,
                                        float acc[4][4], int c0, int fb) {
  #pragma unroll
  for (int i = 0; i < 4; i++)
    #pragma unroll
    for (int j = 0; j < 4; j++) acc[i][j] = 0.f;
  #pragma unroll 4
  for (int k = 0; k < kF; k++) {
    float4 av = *(const float4*)(sA + k * kCp + c0);
    float4 wv = *(const float4*)(sW + k * kF + fb);
    float a[4] = {av.x, av.y, av.z, av.w};
    float w[4] = {wv.x, wv.y, wv.z, wv.w};
    #pragma unroll
    for (int i = 0; i < 4; i++)
      #pragma unroll
      for (int j = 0; j < 4; j++) acc[i][j] += a[i] * w[j];
  }
}

// ---------------------------------------------------------------------------
// Update kernel: one wave (64 thr) per atom, 4c x 4f register tiles.
// FINAL=0: write internal layout [atom][f][12]; FINAL=1: standard [atom][c][f]
// ---------------------------------------------------------------------------
template <int FINAL>
__global__ __launch_bounds__(64) void k_update(
    const float* __restrict__ ypair, const int* __restrict__ seg,
    const float* __restrict__ x_in, const float* __restrict__ W1,
    const float* __restrict__ W2, const float* __restrict__ W3,
    const float* __restrict__ Wg, const float* __restrict__ bg,
    float* __restrict__ x_out) {
  const int atom = blockIdx.x;
  const int tid = threadIdx.x;      // f for elementwise phases
  const int cg = tid >> 4;          // 0..3 (cg==3 inactive in tile phases)
  const int fg = tid & 15;
  const int c0 = cg * 4;
  const int fb = fg * 4;
  const bool act = tid < 48;

  __shared__ __align__(16) float sA[kF * kCp];
  __shared__ __align__(16) float sD[kF * kCp];
  __shared__ __align__(16) float sW[kF * kF];
  __shared__ __align__(16) float sG[192];

  // ---------------- segment aggregation (lane = f) ----------------
  float4 a0 = {0, 0, 0, 0}, a1 = {0, 0, 0, 0}, a2 = {0, 0, 0, 0};
  const int s0 = seg[atom], s1 = seg[atom + 1];
  #pragma unroll 2
  for (int p = s0; p < s1; p++) {
    const float4* yp = (const float4*)(ypair + p * kXs + tid * kCp);
    float4 v0 = yp[0], v1 = yp[1], v2 = yp[2];
    a0.x += v0.x; a0.y += v0.y; a0.z += v0.z; a0.w += v0.w;
    a1.x += v1.x; a1.y += v1.y; a1.z += v1.z; a1.w += v1.w;
    a2.x += v2.x; a2.y += v2.y; a2.z += v2.z; a2.w += v2.w;
  }
  stage_w(W1, sW, tid);
  float dxv[12];
  *(float4*)&dxv[0] = a0; *(float4*)&dxv[4] = a1; *(float4*)&dxv[8] = a2;
  {
    float4* sa = (float4*)(sA + tid * kCp);
    sa[0] = a0; sa[1] = a1; sa[2] = a2;
  }
  __syncthreads();  // 1

  // ---------------- matmul1: ddx = dx @ W1 ----------------
  float acc[4][4];
  if (act) {
    mm_tile(sA, sW, acc, c0, fb);
    #pragma unroll
    for (int j = 0; j < 4; j++) {
      float4 v = {acc[0][j], acc[1][j], acc[2][j], acc[3][j]};
      *(float4*)(sD + (fb + j) * kCp + c0) = v;
    }
  }
  __syncthreads();  // 2

  // ---------------- tp: t2 = dx + CG(dx, ddx) ; stage W2 ----------------
  float ddx[12];
  {
    const float4* sd = (const float4*)(sD + tid * kCp);
    *(float4*)&ddx[0] = sd[0]; *(float4*)&ddx[4] = sd[1]; *(float4*)&ddx[8] = sd[2];
  }
  float t2[12];
  #pragma unroll
  for (int c = 0; c < 9; c++) t2[c] = dxv[c];
  t2[9] = 0.f; t2[10] = 0.f; t2[11] = 0.f;
  #pragma unroll
  for (int e = 0; e < CG.n; e++) {
    t2[CG.c[e]] += CG.v[e] * dxv[CG.a[e]] * ddx[CG.b[e]];
  }
  stage_w(W2, sW, tid);
  {
    float4* sa = (float4*)(sA + tid * kCp);
    sa[0] = *(float4*)&t2[0]; sa[1] = *(float4*)&t2[4]; sa[2] = *(float4*)&t2[8];
  }
  __syncthreads();  // 3

  // ---------------- matmul2: dx2 = t2 @ W2 ----------------
  if (act) {
    mm_tile(sA, sW, acc, c0, fb);
    #pragma unroll
    for (int j = 0; j < 4; j++) {
      float4 v = {acc[0][j], acc[1][j], acc[2][j], acc[3][j]};
      *(float4*)(sD + (fb + j) * kCp + c0) = v;
    }
  }
  __syncthreads();  // 4

  // ---------------- gate: sig(dx2[0] @ Wg + bg) ; stage W3 ----------------
  stage_w(W3, sW, tid);
  if (act) {
    float4 gb = *(const float4*)(bg + cg * 64 + fb);
    float g[4] = {gb.x, gb.y, gb.z, gb.w};
    #pragma unroll 4
    for (int k = 0; k < kF; k++) {
      float a = sD[k * kCp];  // dx2[c=0][k], broadcast
      float4 wv = *(const float4*)(Wg + k * 192 + cg * 64 + fb);
      g[0] += a * wv.x; g[1] += a * wv.y; g[2] += a * wv.z; g[3] += a * wv.w;
    }
    float4 gs;
    gs.x = 1.f / (1.f + expf(-g[0]));
    gs.y = 1.f / (1.f + expf(-g[1]));
    gs.z = 1.f / (1.f + expf(-g[2]));
    gs.w = 1.f / (1.f + expf(-g[3]));
    *(float4*)(sG + cg * 64 + fb) = gs;
  }
  __syncthreads();  // 5

  // ---------------- dx3 = dx2 * gate[lidx] (lane = f) ----------------
  float dx2c[12];
  {
    const float4* sd = (const float4*)(sD + tid * kCp);
    *(float4*)&dx2c[0] = sd[0]; *(float4*)&dx2c[4] = sd[1]; *(float4*)&dx2c[8] = sd[2];
  }
  {
    float g0 = sG[tid], g1 = sG[64 + tid], g2 = sG[128 + tid];
    float dx3[12];
    dx3[0] = dx2c[0] * g0;
    dx3[1] = dx2c[1] * g1;
    dx3[2] = dx2c[2] * g1;
    dx3[3] = dx2c[3] * g1;
    #pragma unroll
    for (int c = 4; c < 9; c++) dx3[c] = dx2c[c] * g2;
    dx3[9] = 0.f; dx3[10] = 0.f; dx3[11] = 0.f;
    float4* sa = (float4*)(sA + tid * kCp);
    sa[0] = *(float4*)&dx3[0]; sa[1] = *(float4*)&dx3[4]; sa[2] = *(float4*)&dx3[8];
  }
  __syncthreads();  // 6

  // ---------------- matmul3 + residual output ----------------
  if (act) {
    mm_tile(sA, sW, acc, c0, fb);
    float rbuf[4][4];
    #pragma unroll
    for (int j = 0; j < 4; j++) {
      float4 v = *(const float4*)(x_in + atom * kXs + (fb + j) * kCp + c0);
      rbuf[j][0] = v.x; rbuf[j][1] = v.y; rbuf[j][2] = v.z; rbuf[j][3] = v.w;
    }
    if (FINAL == 0) {
      #pragma unroll
      for (int j = 0; j < 4; j++) {
        float4 o = {acc[0][j] + rbuf[j][0], acc[1][j] + rbuf[j][1],
                    acc[2][j] + rbuf[j][2], acc[3][j] + rbuf[j][3]};
        *(float4*)(x_out + atom * kXs + (fb + j) * kCp + c0) = o;
      }
    } else {
      #pragma unroll
      for (int i = 0; i < 4; i++) {
        int c = c0 + i;
        if (c < 9) {
          float4 o = {acc[i][0] + rbuf[0][i], acc[i][1] + rbuf[1][i],
                      acc[i][2] + rbuf[2][i], acc[i][3] + rbuf[3][i]};
          *(float4*)(x_out + atom * (kNsh * kF) + c * kF + fb) = o;
        }
      }
    }
  }
}

// ---------------------------------------------------------------------------
// Launch
// ---------------------------------------------------------------------------
extern "C" void kernel_launch(void* const* d_in, const int* in_sizes, int n_in,
                              void* d_out, int out_size, void* d_ws, size_t ws_size,
                              hipStream_t stream) {
  const int* Z        = (const int*)d_in[0];
  const float* rij    = (const float*)d_in[1];
  const int* idx_i    = (const int*)d_in[2];
  const int* idx_j    = (const int*)d_in[3];
  const float* emb    = (const float*)d_in[4];
  const float* Wf     = (const float*)d_in[5];
  const float* bf     = (const float*)d_in[6];
  const float* W1     = (const float*)d_in[7];
  const float* W2     = (const float*)d_in[8];
  const float* W3     = (const float*)d_in[9];
  const float* Wg     = (const float*)d_in[10];
  const float* bg     = (const float*)d_in[11];
  float* x_final = (float*)d_out;

  float* x0    = (float*)d_ws;                       // 768,000
  float* x1    = x0 + kNAtoms * kXs;                 // 768,000
  float* Ypd   = x1 + kNAtoms * kXs;                 // 160,000
  float* Wpair = Ypd + kNPairs * 16;                 // 3,840,000
  float* ypair = Wpair + 2 * kNPairs * 192;          // 7,680,000
  int*   seg   = (int*)(ypair + kNPairs * kXs);      // 1001

  k_pre<<<kPreBlkTotal, 256, 0, stream>>>(
      rij, Wf, bf, Z, emb, idx_i, Ypd, Wpair, x0, seg);

  // t = 0: x0 -> x1 (internal layout)
  k_message<<<kNPairs / 4, 256, 0, stream>>>(x0, idx_j, Ypd, Wpair, ypair);
  k_update<0><<<kNAtoms, 64, 0, stream>>>(
      ypair, seg, x0, W1, W2, W3, Wg, bg, x1);

  // t = 1: x1 -> d_out (standard layout)
  k_message<<<kNPairs / 4, 256, 0, stream>>>(
      x1, idx_j, Ypd, Wpair + kNPairs * 192, ypair);
  k_update<1><<<kNAtoms, 64, 0, stream>>>(
      ypair, seg, x1, W1 + kF * kF, W2 + kF * kF, W3 + kF * kF,
      Wg + kF * 192, bg + 192, x_final);
}

// Round 6
// 152.824 us; speedup vs baseline: 1.4962x; 1.0647x over previous
//
#include <hip/hip_runtime.h>
#include <cmath>

// ---------------------------------------------------------------------------
// Problem constants (from reference)
// ---------------------------------------------------------------------------
constexpr int kNsh    = 9;      // (LMAX+1)^2, LMAX=2
constexpr int kF      = 64;
constexpr int kNrbf   = 20;
constexpr int kNAtoms = 1000;
constexpr int kNPairs = 10000;
constexpr float kCutoffF = 5.0f;
constexpr int kMaxNZ  = 200;
constexpr int kCp     = 12;         // channel dim padded (9 -> 12) for b128
constexpr int kXs     = kF * kCp;   // 768 floats per atom/pair, internal layout

// ---------------------------------------------------------------------------
// Compile-time real Clebsch-Gordan table (mirrors the reference _real_cg)
// ---------------------------------------------------------------------------
struct CGSparse {
  int n;
  int c[kMaxNZ];
  int a[kMaxNZ];
  int b[kMaxNZ];
  float v[kMaxNZ];
};

constexpr double cfact(int n) {
  double r = 1.0;
  for (int i = 2; i <= n; i++) r *= (double)i;
  return r;
}
constexpr double cabs_(double x) { return x < 0 ? -x : x; }
constexpr double csqrt_(double x) {
  if (x <= 0.0) return 0.0;
  double g = x < 1.0 ? 1.0 : x;
  for (int i = 0; i < 60; i++) g = 0.5 * (g + x / g);
  return g;
}

constexpr double cg_cplx(int l1, int m1, int l2, int m2, int l3, int m3) {
  if (m3 != m1 + m2) return 0.0;
  int lo = l1 > l2 ? l1 - l2 : l2 - l1;
  if (l3 < lo || l3 > l1 + l2) return 0.0;
  double pre = csqrt_((2 * l3 + 1) * cfact(l3 + l1 - l2) * cfact(l3 - l1 + l2) *
                      cfact(l1 + l2 - l3) / cfact(l1 + l2 + l3 + 1));
  pre *= csqrt_(cfact(l3 + m3) * cfact(l3 - m3) * cfact(l1 - m1) *
                cfact(l1 + m1) * cfact(l2 - m2) * cfact(l2 + m2));
  double s = 0.0;
  for (int k = 0; k <= l1 + l2 - l3; k++) {
    int d0 = k, d1 = l1 + l2 - l3 - k, d2 = l1 - m1 - k;
    int d3 = l2 + m2 - k, d4 = l3 - l2 + m1 + k, d5 = l3 - l1 - m2 + k;
    if (d0 < 0 || d1 < 0 || d2 < 0 || d3 < 0 || d4 < 0 || d5 < 0) continue;
    double den = cfact(d0) * cfact(d1) * cfact(d2) * cfact(d3) * cfact(d4) * cfact(d5);
    s += ((k % 2) ? -1.0 : 1.0) / den;
  }
  return pre * s;
}

constexpr CGSparse build_cg() {
  CGSparse out{};
  int lidx[9] = {0, 1, 1, 1, 2, 2, 2, 2, 2};
  int midx[9] = {0, -1, 0, 1, -2, -1, 0, 1, 2};
  double Ur[9][9] = {};
  double Ui[9][9] = {};
  for (int l = 0; l <= 2; l++) {
    int base = l * l + l;
    Ur[base][base] = 1.0;
    for (int m = 1; m <= l; m++) {
      double s2 = 1.0 / csqrt_(2.0);
      double sgn = (m % 2) ? -1.0 : 1.0;
      Ur[base + m][base - m] = s2;
      Ur[base + m][base + m] = sgn * s2;
      Ui[base - m][base - m] = s2;
      Ui[base - m][base + m] = -sgn * s2;
    }
  }
  double cgr[9][9][9] = {};
  for (int i = 0; i < 9; i++)
    for (int j = 0; j < 9; j++)
      for (int k = 0; k < 9; k++) {
        double cv = cg_cplx(lidx[i], midx[i], lidx[j], midx[j], lidx[k], midx[k]);
        if (cv == 0.0) continue;
        for (int a2 = 0; a2 < 9; a2++) {
          if (Ur[a2][i] == 0.0 && Ui[a2][i] == 0.0) continue;
          for (int b2 = 0; b2 < 9; b2++) {
            if (Ur[b2][j] == 0.0 && Ui[b2][j] == 0.0) continue;
            for (int c2 = 0; c2 < 9; c2++) {
              if (Ur[c2][k] == 0.0 && Ui[c2][k] == 0.0) continue;
              double ar = Ur[a2][i], ai = Ui[a2][i];
              double br = Ur[b2][j], bi = Ui[b2][j];
              double cr = Ur[c2][k], ci = -Ui[c2][k];  // conj
              double pr = ar * br - ai * bi;
              double pi = ar * bi + ai * br;
              double rr = pr * cr - pi * ci;  // real part
              cgr[c2][a2][b2] += rr * cv;
            }
          }
        }
      }
  int n = 0;
  for (int c2 = 0; c2 < 9; c2++)
    for (int a2 = 0; a2 < 9; a2++)
      for (int b2 = 0; b2 < 9; b2++) {
        bool mask = ((lidx[a2] + lidx[b2]) % 2) == (lidx[c2] % 2);
        double v = mask ? cgr[c2][a2][b2] : 0.0;
        if (cabs_(v) > 1e-9) {
          out.c[n] = c2;
          out.a[n] = a2;
          out.b[n] = b2;
          out.v[n] = (float)v;
          n++;
        }
      }
  out.n = n;
  return out;
}

constexpr CGSparse CG = build_cg();
static_assert(CG.n > 0 && CG.n <= kMaxNZ, "CG table size out of range");

// ---------------------------------------------------------------------------
// Grid partition for the fused pre-kernel
// ---------------------------------------------------------------------------
constexpr int kPreBlkPairs = kNPairs / 4;                     // 2500
constexpr int kPreBlkInit  = kNAtoms * kF / 256;              // 250
constexpr int kPreBlkSeg   = (kNAtoms + 1 + 255) / 256;       // 4
constexpr int kPreBlkTotal = kPreBlkPairs + kPreBlkInit + kPreBlkSeg;

// ---------------------------------------------------------------------------
// Fused pre-kernel: pair geometry+filters | x init (internal layout) | seg
// ---------------------------------------------------------------------------
__global__ __launch_bounds__(256) void k_pre(
    const float* __restrict__ rij, const float* __restrict__ Wf,
    const float* __restrict__ bf, const int* __restrict__ Z,
    const float* __restrict__ emb, const int* __restrict__ idx_i,
    float* __restrict__ Ypd, float* __restrict__ Wpair,
    float* __restrict__ x0, int* __restrict__ seg) {
  const int blk = blockIdx.x;
  if (blk < kPreBlkPairs) {
    // ---- per-pair geometry + radial filters (one wave per pair) ----
    int wv = threadIdx.x >> 6;
    int f = threadIdx.x & 63;
    int p = blk * 4 + wv;
    float rx = rij[3 * p + 0], ry = rij[3 * p + 1], rz = rij[3 * p + 2];
    float d = sqrtf(rx * rx + ry * ry + rz * rz);
    float inv = 1.0f / d;
    float x = rx * inv, y = ry * inv, z = rz * inv;
    const float c0 = 0.28209479177387814f;  // 0.5/sqrt(pi)
    const float c1 = 0.4886025119029199f;   // sqrt(3/(4pi))
    const float c2 = 1.0925484305920792f;   // 0.5*sqrt(15/pi)
    const float c3 = 0.31539156525252005f;  // 0.25*sqrt(5/pi)
    const float c4 = 0.5462742152960396f;   // 0.25*sqrt(15/pi)
    if (f < 9) {
      float yv =
          (f == 0) ? c0 :
          (f == 1) ? c1 * y :
          (f == 2) ? c1 * z :
          (f == 3) ? c1 * x :
          (f == 4) ? c2 * x * y :
          (f == 5) ? c2 * y * z :
          (f == 6) ? c3 * (3.0f * z * z - 1.0f) :
          (f == 7) ? c2 * x * z :
                     c4 * (x * x - y * y);
      Ypd[p * 16 + f] = yv;
    }
    float cut = (d < kCutoffF) ? 0.5f * (cosf(d * (float)(M_PI / 5.0)) + 1.0f) : 0.0f;
    float radial[kNrbf];
    const float width = kCutoffF / (kNrbf - 1);
    const float coef = -0.5f / (width * width);
    #pragma unroll
    for (int k = 0; k < kNrbf; k++) {
      float off = (kCutoffF * k) / (kNrbf - 1);
      float tt = d - off;
      radial[k] = expf(coef * tt * tt);
    }
    #pragma unroll
    for (int t = 0; t < 2; t++) {
      #pragma unroll
      for (int l = 0; l < 3; l++) {
        float w = bf[t * 192 + l * 64 + f];
        #pragma unroll
        for (int k = 0; k < kNrbf; k++) {
          w += radial[k] * Wf[t * (kNrbf * 192) + k * 192 + l * 64 + f];
        }
        Wpair[t * (kNPairs * 192) + p * 192 + l * 64 + f] = w * cut;
      }
    }
  } else if (blk < kPreBlkPairs + kPreBlkInit) {
    // ---- x0 init, internal layout [atom][f][12] ----
    int tid = (blk - kPreBlkPairs) * 256 + threadIdx.x;
    int atom = tid >> 6;
    int f = tid & 63;
    float e = emb[Z[atom] * kF + f];
    float4* b = (float4*)(x0 + atom * kXs + f * kCp);
    b[0] = make_float4(e, 0.f, 0.f, 0.f);
    b[1] = make_float4(0.f, 0.f, 0.f, 0.f);
    b[2] = make_float4(0.f, 0.f, 0.f, 0.f);
  } else {
    // ---- segment offsets: seg[a] = lower_bound(idx_i, a) ----
    int a = (blk - kPreBlkPairs - kPreBlkInit) * 256 + threadIdx.x;
    if (a <= kNAtoms) {
      int lo = 0, hi = kNPairs;
      while (lo < hi) {
        int mid = (lo + hi) >> 1;
        if (idx_i[mid] < a) lo = mid + 1; else hi = mid;
      }
      seg[a] = lo;
    }
  }
}

// ---------------------------------------------------------------------------
// Message kernel: one wave per pair -> ypair[p][f][12] (b128 gather + store)
// ---------------------------------------------------------------------------
__global__ __launch_bounds__(256) void k_message(
    const float* __restrict__ x_in, const int* __restrict__ idx_j,
    const float* __restrict__ Ypd, const float* __restrict__ Wpair,
    float* __restrict__ ypair) {
  const int wv = threadIdx.x >> 6;
  const int f = threadIdx.x & 63;
  const int p = blockIdx.x * 4 + wv;
  const float* Yp = Ypd + p * 16;
  const float* Wp = Wpair + p * 192;
  float Wl0 = Wp[f], Wl1 = Wp[64 + f], Wl2 = Wp[128 + f];
  const int j = __builtin_amdgcn_readfirstlane(idx_j[p]);
  const float* xj = x_in + j * kXs + f * kCp;
  float xv[12];
  *(float4*)&xv[0] = *(const float4*)(xj + 0);
  *(float4*)&xv[4] = *(const float4*)(xj + 4);
  *(float4*)&xv[8] = *(const float4*)(xj + 8);
  float YW[9];
  YW[0] = Yp[0] * Wl0;
  YW[1] = Yp[1] * Wl1;
  YW[2] = Yp[2] * Wl1;
  YW[3] = Yp[3] * Wl1;
  #pragma unroll
  for (int b = 4; b < 9; b++) YW[b] = Yp[b] * Wl2;
  float y[12] = {0, 0, 0, 0, 0, 0, 0, 0, 0, 0, 0, 0};
  #pragma unroll
  for (int e = 0; e < CG.n; e++) {
    y[CG.c[e]] += CG.v[e] * YW[CG.b[e]] * xv[CG.a[e]];
  }
  float* yp = ypair + p * kXs + f * kCp;
  *(float4*)(yp + 0) = *(float4*)&y[0];
  *(float4*)(yp + 4) = *(float4*)&y[4];
  *(float4*)(yp + 8) = *(float4*)&y[8];
}

// ---------------------------------------------------------------------------
// Update kernel helpers
// ---------------------------------------------------------------------------
// 256-thread staging of a 64x64 weight matrix into LDS
__device__ __forceinline__ void stage_w(const float* __restrict__ W,
                                        float* __restrict__ sW, int tid) {
  const float4* g4 = (const float4*)W;
  float4* s4 = (float4*)sW;
  #pragma unroll
  for (int r = 0; r < 4; r++) s4[r * 256 + tid] = g4[r * 256 + tid];
}

// k-split matmul partial: wave computes full 12c x 64f tile over 16 k-slices.
// Lanes: cg = lane>>4 (0..3, cg==3 idle), fg = lane&15. Tile 4c x 4f.
// sA: f-major A staging (sA[k*12+c] = A[c][k]); sW: W[k][f]; out: f-major.
__device__ __forceinline__ void mm_phase(const float* __restrict__ sA,
                                         const float* __restrict__ sW,
                                         float* __restrict__ sRw,
                                         int k0, int cg, int fb) {
  if (cg >= 3) return;
  const int c0 = cg * 4;
  float acc[4][4];
  #pragma unroll
  for (int i = 0; i < 4; i++)
    #pragma unroll
    for (int j = 0; j < 4; j++) acc[i][j] = 0.f;
  #pragma unroll 4
  for (int kk = 0; kk < 16; kk++) {
    int k = k0 + kk;
    float4 av = *(const float4*)(sA + k * kCp + c0);
    float4 wv = *(const float4*)(sW + k * kF + fb);
    float a[4] = {av.x, av.y, av.z, av.w};
    float w[4] = {wv.x, wv.y, wv.z, wv.w};
    #pragma unroll
    for (int i = 0; i < 4; i++)
      #pragma unroll
      for (int j = 0; j < 4; j++) acc[i][j] += a[i] * w[j];
  }
  #pragma unroll
  for (int j = 0; j < 4; j++) {
    float4 v = {acc[0][j], acc[1][j], acc[2][j], acc[3][j]};
    *(float4*)(sRw + (fb + j) * kCp + c0) = v;
  }
}

// ---------------------------------------------------------------------------
// Update kernel: one block (256 thr = 4 waves) per atom. Every phase 4-way
// wave-parallel: aggregation pair-split, matmuls k-split (reg tiles + LDS
// partial reduce), gate k-split. FINAL=0: internal [f][12] out; FINAL=1:
// standard [c][f] out.
// ---------------------------------------------------------------------------
template <int FINAL>
__global__ __launch_bounds__(256) void k_update(
    const float* __restrict__ ypair, const int* __restrict__ seg,
    const float* __restrict__ x_in, const float* __restrict__ W1,
    const float* __restrict__ W2, const float* __restrict__ W3,
    const float* __restrict__ Wg, const float* __restrict__ bg,
    float* __restrict__ x_out) {
  const int atom = blockIdx.x;
  const int tid = threadIdx.x;
  const int wv = tid >> 6;          // wave 0..3
  const int lane = tid & 63;
  const int cg = lane >> 4;         // 0..3 (3 idle in mm)
  const int fg = lane & 15;
  const int fb = fg * 4;
  const int k0 = wv * 16;           // k-range for this wave

  __shared__ __align__(16) float sA[kF * kCp];     // 3 KB  A staging, f-major
  __shared__ __align__(16) float sW[kF * kF];      // 16 KB weight staging
  __shared__ __align__(16) float sR[4][kF * kCp];  // 12 KB per-wave partials
  __shared__ __align__(16) float sGp[4][192];      // 3 KB  gate partials

  // stage W1 early (loads overlap aggregation)
  stage_w(W1, sW, tid);

  // ---------------- aggregation: pairs split across 4 waves ----------------
  {
    float4 a0 = {0, 0, 0, 0}, a1 = {0, 0, 0, 0}, a2 = {0, 0, 0, 0};
    const int s0 = seg[atom], s1 = seg[atom + 1];
    #pragma unroll 2
    for (int p = s0 + wv; p < s1; p += 4) {
      const float4* yp = (const float4*)(ypair + p * kXs + lane * kCp);
      float4 v0 = yp[0], v1 = yp[1], v2 = yp[2];
      a0.x += v0.x; a0.y += v0.y; a0.z += v0.z; a0.w += v0.w;
      a1.x += v1.x; a1.y += v1.y; a1.z += v1.z; a1.w += v1.w;
      a2.x += v2.x; a2.y += v2.y; a2.z += v2.z; a2.w += v2.w;
    }
    float4* r4 = (float4*)(sR[wv] + lane * kCp);
    r4[0] = a0; r4[1] = a1; r4[2] = a2;
  }
  __syncthreads();  // B1
  // reduce partials -> sA (dx, f-major); 3 floats per thread
  {
    const int i = tid * 3;
    #pragma unroll
    for (int d = 0; d < 3; d++) {
      sA[i + d] = sR[0][i + d] + sR[1][i + d] + sR[2][i + d] + sR[3][i + d];
    }
  }
  __syncthreads();  // B2

  // ---------------- matmul1: ddx = dx @ W1 (k-split) ----------------
  mm_phase(sA, sW, sR[wv], k0, cg, fb);
  __syncthreads();  // B3

  // ---------------- stage W2 ; wave0: tp (t2 = dx + CG(dx, ddx)) ----------
  stage_w(W2, sW, tid);
  if (wv == 0) {
    float dxv[12], ddx[12];
    {
      const float4* sa = (const float4*)(sA + lane * kCp);
      *(float4*)&dxv[0] = sa[0]; *(float4*)&dxv[4] = sa[1]; *(float4*)&dxv[8] = sa[2];
    }
    #pragma unroll
    for (int c = 0; c < 12; c++) {
      ddx[c] = sR[0][lane * kCp + c] + sR[1][lane * kCp + c] +
               sR[2][lane * kCp + c] + sR[3][lane * kCp + c];
    }
    float t2[12];
    #pragma unroll
    for (int c = 0; c < 9; c++) t2[c] = dxv[c];
    t2[9] = 0.f; t2[10] = 0.f; t2[11] = 0.f;
    #pragma unroll
    for (int e = 0; e < CG.n; e++) {
      t2[CG.c[e]] += CG.v[e] * dxv[CG.a[e]] * ddx[CG.b[e]];
    }
    float4* sa = (float4*)(sA + lane * kCp);
    sa[0] = *(float4*)&t2[0]; sa[1] = *(float4*)&t2[4]; sa[2] = *(float4*)&t2[8];
  }
  __syncthreads();  // B4

  // ---------------- matmul2: dx2 = t2 @ W2 (k-split) ----------------
  mm_phase(sA, sW, sR[wv], k0, cg, fb);
  __syncthreads();  // B5

  // ---------------- stage W3 ; gate partials (k-split) ----------------
  stage_w(W3, sW, tid);
  {
    float g0 = 0.f, g1 = 0.f, g2 = 0.f;
    #pragma unroll 4
    for (int kk = 0; kk < 16; kk++) {
      int k = k0 + kk;
      float a = sR[0][k * kCp] + sR[1][k * kCp] + sR[2][k * kCp] + sR[3][k * kCp];
      g0 += a * Wg[k * 192 + lane];
      g1 += a * Wg[k * 192 + 64 + lane];
      g2 += a * Wg[k * 192 + 128 + lane];
    }
    sGp[wv][lane] = g0;
    sGp[wv][64 + lane] = g1;
    sGp[wv][128 + lane] = g2;
  }
  __syncthreads();  // B6

  // ---------------- wave0: dx3 = dx2 * sigmoid(gate)[lidx] -> sA ----------
  if (wv == 0) {
    float dx2v[12];
    #pragma unroll
    for (int c = 0; c < 12; c++) {
      dx2v[c] = sR[0][lane * kCp + c] + sR[1][lane * kCp + c] +
                sR[2][lane * kCp + c] + sR[3][lane * kCp + c];
    }
    float g0 = bg[lane] + sGp[0][lane] + sGp[1][lane] + sGp[2][lane] + sGp[3][lane];
    float g1 = bg[64 + lane] + sGp[0][64 + lane] + sGp[1][64 + lane] +
               sGp[2][64 + lane] + sGp[3][64 + lane];
    float g2 = bg[128 + lane] + sGp[0][128 + lane] + sGp[1][128 + lane] +
               sGp[2][128 + lane] + sGp[3][128 + lane];
    g0 = 1.f / (1.f + expf(-g0));
    g1 = 1.f / (1.f + expf(-g1));
    g2 = 1.f / (1.f + expf(-g2));
    float dx3[12];
    dx3[0] = dx2v[0] * g0;
    dx3[1] = dx2v[1] * g1;
    dx3[2] = dx2v[2] * g1;
    dx3[3] = dx2v[3] * g1;
    #pragma unroll
    for (int c = 4; c < 9; c++) dx3[c] = dx2v[c] * g2;
    dx3[9] = 0.f; dx3[10] = 0.f; dx3[11] = 0.f;
    float4* sa = (float4*)(sA + lane * kCp);
    sa[0] = *(float4*)&dx3[0]; sa[1] = *(float4*)&dx3[4]; sa[2] = *(float4*)&dx3[8];
  }
  __syncthreads();  // B7

  // ---------------- matmul3: out = dx3 @ W3 (k-split) ----------------
  mm_phase(sA, sW, sR[wv], k0, cg, fb);
  __syncthreads();  // B8

  // ---------------- residual output ----------------
  if (FINAL == 0) {
    const int i = tid * 3;
    #pragma unroll
    for (int d = 0; d < 3; d++) {
      float v = sR[0][i + d] + sR[1][i + d] + sR[2][i + d] + sR[3][i + d] +
                x_in[atom * kXs + i + d];
      x_out[atom * kXs + i + d] = v;
    }
  } else {
    for (int i = tid; i < kNsh * kF; i += 256) {
      int c = i >> 6, f = i & 63;
      int o = f * kCp + c;
      float v = sR[0][o] + sR[1][o] + sR[2][o] + sR[3][o] +
                x_in[atom * kXs + o];
      x_out[atom * (kNsh * kF) + i] = v;
    }
  }
}

// ---------------------------------------------------------------------------
// Launch
// ---------------------------------------------------------------------------
extern "C" void kernel_launch(void* const* d_in, const int* in_sizes, int n_in,
                              void* d_out, int out_size, void* d_ws, size_t ws_size,
                              hipStream_t stream) {
  const int* Z        = (const int*)d_in[0];
  const float* rij    = (const float*)d_in[1];
  const int* idx_i    = (const int*)d_in[2];
  const int* idx_j    = (const int*)d_in[3];
  const float* emb    = (const float*)d_in[4];
  const float* Wf     = (const float*)d_in[5];
  const float* bf     = (const float*)d_in[6];
  const float* W1     = (const float*)d_in[7];
  const float* W2     = (const float*)d_in[8];
  const float* W3     = (const float*)d_in[9];
  const float* Wg     = (const float*)d_in[10];
  const float* bg     = (const float*)d_in[11];
  float* x_final = (float*)d_out;

  float* x0    = (float*)d_ws;                       // 768,000
  float* x1    = x0 + kNAtoms * kXs;                 // 768,000
  float* Ypd   = x1 + kNAtoms * kXs;                 // 160,000
  float* Wpair = Ypd + kNPairs * 16;                 // 3,840,000
  float* ypair = Wpair + 2 * kNPairs * 192;          // 7,680,000
  int*   seg   = (int*)(ypair + kNPairs * kXs);      // 1001

  k_pre<<<kPreBlkTotal, 256, 0, stream>>>(
      rij, Wf, bf, Z, emb, idx_i, Ypd, Wpair, x0, seg);

  // t = 0: x0 -> x1 (internal layout)
  k_message<<<kNPairs / 4, 256, 0, stream>>>(x0, idx_j, Ypd, Wpair, ypair);
  k_update<0><<<kNAtoms, 256, 0, stream>>>(
      ypair, seg, x0, W1, W2, W3, Wg, bg, x1);

  // t = 1: x1 -> d_out (standard layout)
  k_message<<<kNPairs / 4, 256, 0, stream>>>(
      x1, idx_j, Ypd, Wpair + kNPairs * 192, ypair);
  k_update<1><<<kNAtoms, 256, 0, stream>>>(
      ypair, seg, x1, W1 + kF * kF, W2 + kF * kF, W3 + kF * kF,
      Wg + kF * 192, bg + 192, x_final);
}

// Round 8
// 126.613 us; speedup vs baseline: 1.8059x; 1.2070x over previous
//
#include <hip/hip_runtime.h>
#include <cmath>

// ---------------------------------------------------------------------------
// Problem constants (from reference)
// ---------------------------------------------------------------------------
constexpr int kNsh    = 9;      // (LMAX+1)^2, LMAX=2
constexpr int kF      = 64;
constexpr int kNrbf   = 20;
constexpr int kNAtoms = 1000;
constexpr int kNPairs = 10000;
constexpr float kCutoffF = 5.0f;
constexpr int kMaxNZ  = 200;
constexpr int kCp     = 12;         // channel dim padded (9 -> 12) for b128
constexpr int kXs     = kF * kCp;   // 768 floats per atom, internal layout

// ---------------------------------------------------------------------------
// Compile-time real Clebsch-Gordan table (mirrors the reference _real_cg)
// ---------------------------------------------------------------------------
struct CGSparse {
  int n;
  int c[kMaxNZ];
  int a[kMaxNZ];
  int b[kMaxNZ];
  float v[kMaxNZ];
};

constexpr double cfact(int n) {
  double r = 1.0;
  for (int i = 2; i <= n; i++) r *= (double)i;
  return r;
}
constexpr double cabs_(double x) { return x < 0 ? -x : x; }
constexpr double csqrt_(double x) {
  if (x <= 0.0) return 0.0;
  double g = x < 1.0 ? 1.0 : x;
  for (int i = 0; i < 60; i++) g = 0.5 * (g + x / g);
  return g;
}

constexpr double cg_cplx(int l1, int m1, int l2, int m2, int l3, int m3) {
  if (m3 != m1 + m2) return 0.0;
  int lo = l1 > l2 ? l1 - l2 : l2 - l1;
  if (l3 < lo || l3 > l1 + l2) return 0.0;
  double pre = csqrt_((2 * l3 + 1) * cfact(l3 + l1 - l2) * cfact(l3 - l1 + l2) *
                      cfact(l1 + l2 - l3) / cfact(l1 + l2 + l3 + 1));
  pre *= csqrt_(cfact(l3 + m3) * cfact(l3 - m3) * cfact(l1 - m1) *
                cfact(l1 + m1) * cfact(l2 - m2) * cfact(l2 + m2));
  double s = 0.0;
  for (int k = 0; k <= l1 + l2 - l3; k++) {
    int d0 = k, d1 = l1 + l2 - l3 - k, d2 = l1 - m1 - k;
    int d3 = l2 + m2 - k, d4 = l3 - l2 + m1 + k, d5 = l3 - l1 - m2 + k;
    if (d0 < 0 || d1 < 0 || d2 < 0 || d3 < 0 || d4 < 0 || d5 < 0) continue;
    double den = cfact(d0) * cfact(d1) * cfact(d2) * cfact(d3) * cfact(d4) * cfact(d5);
    s += ((k % 2) ? -1.0 : 1.0) / den;
  }
  return pre * s;
}

constexpr CGSparse build_cg() {
  CGSparse out{};
  int lidx[9] = {0, 1, 1, 1, 2, 2, 2, 2, 2};
  int midx[9] = {0, -1, 0, 1, -2, -1, 0, 1, 2};
  double Ur[9][9] = {};
  double Ui[9][9] = {};
  for (int l = 0; l <= 2; l++) {
    int base = l * l + l;
    Ur[base][base] = 1.0;
    for (int m = 1; m <= l; m++) {
      double s2 = 1.0 / csqrt_(2.0);
      double sgn = (m % 2) ? -1.0 : 1.0;
      Ur[base + m][base - m] = s2;
      Ur[base + m][base + m] = sgn * s2;
      Ui[base - m][base - m] = s2;
      Ui[base - m][base + m] = -sgn * s2;
    }
  }
  double cgr[9][9][9] = {};
  for (int i = 0; i < 9; i++)
    for (int j = 0; j < 9; j++)
      for (int k = 0; k < 9; k++) {
        double cv = cg_cplx(lidx[i], midx[i], lidx[j], midx[j], lidx[k], midx[k]);
        if (cv == 0.0) continue;
        for (int a2 = 0; a2 < 9; a2++) {
          if (Ur[a2][i] == 0.0 && Ui[a2][i] == 0.0) continue;
          for (int b2 = 0; b2 < 9; b2++) {
            if (Ur[b2][j] == 0.0 && Ui[b2][j] == 0.0) continue;
            for (int c2 = 0; c2 < 9; c2++) {
              if (Ur[c2][k] == 0.0 && Ui[c2][k] == 0.0) continue;
              double ar = Ur[a2][i], ai = Ui[a2][i];
              double br = Ur[b2][j], bi = Ui[b2][j];
              double cr = Ur[c2][k], ci = -Ui[c2][k];  // conj
              double pr = ar * br - ai * bi;
              double pi = ar * bi + ai * br;
              double rr = pr * cr - pi * ci;  // real part
              cgr[c2][a2][b2] += rr * cv;
            }
          }
        }
      }
  int n = 0;
  for (int c2 = 0; c2 < 9; c2++)
    for (int a2 = 0; a2 < 9; a2++)
      for (int b2 = 0; b2 < 9; b2++) {
        bool mask = ((lidx[a2] + lidx[b2]) % 2) == (lidx[c2] % 2);
        double v = mask ? cgr[c2][a2][b2] : 0.0;
        if (cabs_(v) > 1e-9) {
          out.c[n] = c2;
          out.a[n] = a2;
          out.b[n] = b2;
          out.v[n] = (float)v;
          n++;
        }
      }
  out.n = n;
  return out;
}

constexpr CGSparse CG = build_cg();
static_assert(CG.n > 0 && CG.n <= kMaxNZ, "CG table size out of range");

// ---------------------------------------------------------------------------
// k_pre: pair geometry + radial filters (both t) | segment offsets
// ---------------------------------------------------------------------------
constexpr int kPreBlkPairs = kNPairs / 4;                 // 2500
constexpr int kPreBlkSeg   = (kNAtoms + 1 + 255) / 256;   // 4
constexpr int kPreBlkTotal = kPreBlkPairs + kPreBlkSeg;

__global__ __launch_bounds__(256) void k_pre(
    const float* __restrict__ rij, const float* __restrict__ Wf,
    const float* __restrict__ bf, const int* __restrict__ idx_i,
    float* __restrict__ Ypd, float* __restrict__ Wpair,
    int* __restrict__ seg) {
  const int blk = blockIdx.x;
  if (blk < kPreBlkPairs) {
    int wv = threadIdx.x >> 6;
    int f = threadIdx.x & 63;
    int p = blk * 4 + wv;
    float rx = rij[3 * p + 0], ry = rij[3 * p + 1], rz = rij[3 * p + 2];
    float d = sqrtf(rx * rx + ry * ry + rz * rz);
    float inv = 1.0f / d;
    float x = rx * inv, y = ry * inv, z = rz * inv;
    const float c0 = 0.28209479177387814f;  // 0.5/sqrt(pi)
    const float c1 = 0.4886025119029199f;   // sqrt(3/(4pi))
    const float c2 = 1.0925484305920792f;   // 0.5*sqrt(15/pi)
    const float c3 = 0.31539156525252005f;  // 0.25*sqrt(5/pi)
    const float c4 = 0.5462742152960396f;   // 0.25*sqrt(15/pi)
    if (f < 9) {
      float yv =
          (f == 0) ? c0 :
          (f == 1) ? c1 * y :
          (f == 2) ? c1 * z :
          (f == 3) ? c1 * x :
          (f == 4) ? c2 * x * y :
          (f == 5) ? c2 * y * z :
          (f == 6) ? c3 * (3.0f * z * z - 1.0f) :
          (f == 7) ? c2 * x * z :
                     c4 * (x * x - y * y);
      Ypd[p * 16 + f] = yv;
    }
    float cut = (d < kCutoffF) ? 0.5f * (cosf(d * (float)(M_PI / 5.0)) + 1.0f) : 0.0f;
    float radial[kNrbf];
    const float width = kCutoffF / (kNrbf - 1);
    const float coef = -0.5f / (width * width);
    #pragma unroll
    for (int k = 0; k < kNrbf; k++) {
      float off = (kCutoffF * k) / (kNrbf - 1);
      float tt = d - off;
      radial[k] = expf(coef * tt * tt);
    }
    #pragma unroll
    for (int t = 0; t < 2; t++) {
      #pragma unroll
      for (int l = 0; l < 3; l++) {
        float w = bf[t * 192 + l * 64 + f];
        #pragma unroll
        for (int k = 0; k < kNrbf; k++) {
          w += radial[k] * Wf[t * (kNrbf * 192) + k * 192 + l * 64 + f];
        }
        Wpair[t * (kNPairs * 192) + p * 192 + l * 64 + f] = w * cut;
      }
    }
  } else {
    int a = (blk - kPreBlkPairs) * 256 + threadIdx.x;
    if (a <= kNAtoms) {
      int lo = 0, hi = kNPairs;
      while (lo < hi) {
        int mid = (lo + hi) >> 1;
        if (idx_i[mid] < a) lo = mid + 1; else hi = mid;
      }
      seg[a] = lo;
    }
  }
}

// ---------------------------------------------------------------------------
// Helpers
// ---------------------------------------------------------------------------
__device__ __forceinline__ void stage_w(const float* __restrict__ W,
                                        float* __restrict__ sW, int tid) {
  const float4* g4 = (const float4*)W;
  float4* s4 = (float4*)sW;
  #pragma unroll
  for (int r = 0; r < 4; r++) s4[r * 256 + tid] = g4[r * 256 + tid];
}

// k-split matmul partial: wave computes full 12c x 64f tile over 16 k-slices.
__device__ __forceinline__ void mm_phase(const float* __restrict__ sA,
                                         const float* __restrict__ sW,
                                         float* __restrict__ sRw,
                                         int k0, int cgi, int fb) {
  if (cgi >= 3) return;
  const int c0 = cgi * 4;
  float acc[4][4];
  #pragma unroll
  for (int i = 0; i < 4; i++)
    #pragma unroll
    for (int j = 0; j < 4; j++) acc[i][j] = 0.f;
  #pragma unroll 4
  for (int kk = 0; kk < 16; kk++) {
    int k = k0 + kk;
    float4 av = *(const float4*)(sA + k * kCp + c0);
    float4 wv = *(const float4*)(sW + k * kF + fb);
    float a[4] = {av.x, av.y, av.z, av.w};
    float w[4] = {wv.x, wv.y, wv.z, wv.w};
    #pragma unroll
    for (int i = 0; i < 4; i++)
      #pragma unroll
      for (int j = 0; j < 4; j++) acc[i][j] += a[i] * w[j];
  }
  #pragma unroll
  for (int j = 0; j < 4; j++) {
    float4 v = {acc[0][j], acc[1][j], acc[2][j], acc[3][j]};
    *(float4*)(sRw + (fb + j) * kCp + c0) = v;
  }
}

// ---------------------------------------------------------------------------
// k_inter<T>: fused message + update, one block (4 waves) per atom.
// T==0: gather from emb[Z[j]] (x0 never materialized), write x1 internal
// layout [f][12]. T==1: gather from x1, write standard [c][f] to out.
// ---------------------------------------------------------------------------
template <int T>
__global__ __launch_bounds__(256) void k_inter(
    const float* __restrict__ Ypd, const float* __restrict__ Wpt,
    const int* __restrict__ seg, const int* __restrict__ idx_j,
    const int* __restrict__ Z, const float* __restrict__ emb,
    const float* __restrict__ x_in, const float* __restrict__ W1,
    const float* __restrict__ W2, const float* __restrict__ W3,
    const float* __restrict__ Wg, const float* __restrict__ bg,
    float* __restrict__ x_out) {
  const int atom = blockIdx.x;
  const int tid = threadIdx.x;
  const int wv = tid >> 6;          // wave 0..3
  const int lane = tid & 63;
  const int cgi = lane >> 4;        // 0..3 (3 idle in mm)
  const int fb = (lane & 15) * 4;
  const int k0 = wv * 16;           // k-range for this wave

  __shared__ __align__(16) float sA[kF * kCp];     // 3 KB  A staging, f-major
  __shared__ __align__(16) float sW[kF * kF];      // 16 KB weight staging
  __shared__ __align__(16) float sR[4][kF * kCp];  // 12 KB per-wave partials
  __shared__ __align__(16) float sGp[4][192];      // 3 KB  gate partials

  stage_w(W1, sW, tid);  // overlaps the message gather

  // ---- message + aggregation (pairs split across 4 waves) ----
  {
    float y[12];
    #pragma unroll
    for (int c = 0; c < 12; c++) y[c] = 0.f;
    const int s0 = seg[atom], s1 = seg[atom + 1];
    for (int p0 = s0 + wv; p0 < s1; p0 += 4) {
      const int p = __builtin_amdgcn_readfirstlane(p0);
      const int j = __builtin_amdgcn_readfirstlane(idx_j[p]);
      const float* Wp = Wpt + p * 192;
      float Wl0 = Wp[lane], Wl1 = Wp[64 + lane], Wl2 = Wp[128 + lane];
      const float* Yp = Ypd + p * 16;
      float YW[9];
      YW[0] = Yp[0] * Wl0;
      YW[1] = Yp[1] * Wl1;
      YW[2] = Yp[2] * Wl1;
      YW[3] = Yp[3] * Wl1;
      #pragma unroll
      for (int b = 4; b < 9; b++) YW[b] = Yp[b] * Wl2;
      if (T == 0) {
        // x[j] = emb[Z[j]] in channel 0 only: CG folds to a==0 entries
        float e = emb[Z[j] * kF + lane];
        #pragma unroll
        for (int q = 0; q < CG.n; q++) {
          if (CG.a[q] == 0) y[CG.c[q]] += CG.v[q] * YW[CG.b[q]] * e;
        }
      } else {
        const float* xj = x_in + j * kXs + lane * kCp;
        float xv[12];
        *(float4*)&xv[0] = *(const float4*)(xj + 0);
        *(float4*)&xv[4] = *(const float4*)(xj + 4);
        *(float4*)&xv[8] = *(const float4*)(xj + 8);
        #pragma unroll
        for (int q = 0; q < CG.n; q++) {
          y[CG.c[q]] += CG.v[q] * YW[CG.b[q]] * xv[CG.a[q]];
        }
      }
    }
    float4* r4 = (float4*)(sR[wv] + lane * kCp);
    r4[0] = *(float4*)&y[0];
    r4[1] = *(float4*)&y[4];
    r4[2] = *(float4*)&y[8];
  }
  __syncthreads();  // B1
  // reduce partials -> sA (dx, f-major); 3 floats per thread
  {
    const int i = tid * 3;
    #pragma unroll
    for (int d = 0; d < 3; d++) {
      sA[i + d] = sR[0][i + d] + sR[1][i + d] + sR[2][i + d] + sR[3][i + d];
    }
  }
  __syncthreads();  // B2

  // ---- matmul1: ddx = dx @ W1 (k-split) ----
  mm_phase(sA, sW, sR[wv], k0, cgi, fb);
  __syncthreads();  // B3

  // ---- stage W2 ; wave0: tp (t2 = dx + CG(dx, ddx)) ----
  stage_w(W2, sW, tid);
  if (wv == 0) {
    float dxv[12], ddx[12];
    {
      const float4* sa = (const float4*)(sA + lane * kCp);
      *(float4*)&dxv[0] = sa[0];
      *(float4*)&dxv[4] = sa[1];
      *(float4*)&dxv[8] = sa[2];
    }
    #pragma unroll
    for (int c = 0; c < 12; c++) {
      ddx[c] = sR[0][lane * kCp + c] + sR[1][lane * kCp + c] +
               sR[2][lane * kCp + c] + sR[3][lane * kCp + c];
    }
    float t2[12];
    #pragma unroll
    for (int c = 0; c < 9; c++) t2[c] = dxv[c];
    t2[9] = 0.f; t2[10] = 0.f; t2[11] = 0.f;
    #pragma unroll
    for (int q = 0; q < CG.n; q++) {
      t2[CG.c[q]] += CG.v[q] * dxv[CG.a[q]] * ddx[CG.b[q]];
    }
    float4* sa = (float4*)(sA + lane * kCp);
    sa[0] = *(float4*)&t2[0];
    sa[1] = *(float4*)&t2[4];
    sa[2] = *(float4*)&t2[8];
  }
  __syncthreads();  // B4

  // ---- matmul2: dx2 = t2 @ W2 (k-split) ----
  mm_phase(sA, sW, sR[wv], k0, cgi, fb);
  __syncthreads();  // B5

  // ---- stage W3 ; gate partials (k-split) ----
  stage_w(W3, sW, tid);
  {
    float g0 = 0.f, g1 = 0.f, g2 = 0.f;
    #pragma unroll 4
    for (int kk = 0; kk < 16; kk++) {
      int k = k0 + kk;
      float a = sR[0][k * kCp] + sR[1][k * kCp] + sR[2][k * kCp] + sR[3][k * kCp];
      g0 += a * Wg[k * 192 + lane];
      g1 += a * Wg[k * 192 + 64 + lane];
      g2 += a * Wg[k * 192 + 128 + lane];
    }
    sGp[wv][lane] = g0;
    sGp[wv][64 + lane] = g1;
    sGp[wv][128 + lane] = g2;
  }
  __syncthreads();  // B6

  // ---- wave0: dx3 = dx2 * sigmoid(gate)[lidx] -> sA ----
  if (wv == 0) {
    float dx2v[12];
    #pragma unroll
    for (int c = 0; c < 12; c++) {
      dx2v[c] = sR[0][lane * kCp + c] + sR[1][lane * kCp + c] +
                sR[2][lane * kCp + c] + sR[3][lane * kCp + c];
    }
    float g0 = bg[lane] + sGp[0][lane] + sGp[1][lane] + sGp[2][lane] + sGp[3][lane];
    float g1 = bg[64 + lane] + sGp[0][64 + lane] + sGp[1][64 + lane] +
               sGp[2][64 + lane] + sGp[3][64 + lane];
    float g2 = bg[128 + lane] + sGp[0][128 + lane] + sGp[1][128 + lane] +
               sGp[2][128 + lane] + sGp[3][128 + lane];
    g0 = 1.f / (1.f + expf(-g0));
    g1 = 1.f / (1.f + expf(-g1));
    g2 = 1.f / (1.f + expf(-g2));
    float dx3[12];
    dx3[0] = dx2v[0] * g0;
    dx3[1] = dx2v[1] * g1;
    dx3[2] = dx2v[2] * g1;
    dx3[3] = dx2v[3] * g1;
    #pragma unroll
    for (int c = 4; c < 9; c++) dx3[c] = dx2v[c] * g2;
    dx3[9] = 0.f; dx3[10] = 0.f; dx3[11] = 0.f;
    float4* sa = (float4*)(sA + lane * kCp);
    sa[0] = *(float4*)&dx3[0];
    sa[1] = *(float4*)&dx3[4];
    sa[2] = *(float4*)&dx3[8];
  }
  __syncthreads();  // B7

  // ---- matmul3: out = dx3 @ W3 (k-split) ----
  mm_phase(sA, sW, sR[wv], k0, cgi, fb);
  __syncthreads();  // B8

  // ---- residual output ----
  if (T == 0) {
    // residual = x0 = emb[Z[atom]] in channel 0 only
    const int zi = Z[atom];
    const int i = tid * 3;
    #pragma unroll
    for (int d = 0; d < 3; d++) {
      const int idx = i + d;
      const int c = idx % kCp;
      float v = sR[0][idx] + sR[1][idx] + sR[2][idx] + sR[3][idx];
      if (c == 0) v += emb[zi * kF + idx / kCp];
      x_out[atom * kXs + idx] = v;
    }
  } else {
    for (int i = tid; i < kNsh * kF; i += 256) {
      int c = i >> 6, f = i & 63;
      int o = f * kCp + c;
      float v = sR[0][o] + sR[1][o] + sR[2][o] + sR[3][o] +
                x_in[atom * kXs + o];
      x_out[atom * (kNsh * kF) + i] = v;
    }
  }
}

// ---------------------------------------------------------------------------
// Launch: 3 dispatches (kernel boundaries provide all coherence)
// ---------------------------------------------------------------------------
extern "C" void kernel_launch(void* const* d_in, const int* in_sizes, int n_in,
                              void* d_out, int out_size, void* d_ws, size_t ws_size,
                              hipStream_t stream) {
  const int* Z        = (const int*)d_in[0];
  const float* rij    = (const float*)d_in[1];
  const int* idx_i    = (const int*)d_in[2];
  const int* idx_j    = (const int*)d_in[3];
  const float* emb    = (const float*)d_in[4];
  const float* Wf     = (const float*)d_in[5];
  const float* bf     = (const float*)d_in[6];
  const float* W1     = (const float*)d_in[7];
  const float* W2     = (const float*)d_in[8];
  const float* W3     = (const float*)d_in[9];
  const float* Wg     = (const float*)d_in[10];
  const float* bg     = (const float*)d_in[11];
  float* out = (float*)d_out;

  float* x1    = (float*)d_ws;                       // 768,000
  float* Ypd   = x1 + kNAtoms * kXs;                 // 160,000
  float* Wpair = Ypd + kNPairs * 16;                 // 3,840,000
  int*   seg   = (int*)(Wpair + 2 * kNPairs * 192);  // 1001

  k_pre<<<kPreBlkTotal, 256, 0, stream>>>(rij, Wf, bf, idx_i, Ypd, Wpair, seg);

  // t = 0: emb-gather -> x1 (internal layout)
  k_inter<0><<<kNAtoms, 256, 0, stream>>>(
      Ypd, Wpair, seg, idx_j, Z, emb, x1,
      W1, W2, W3, Wg, bg, x1);

  // t = 1: x1-gather -> d_out (standard layout)
  k_inter<1><<<kNAtoms, 256, 0, stream>>>(
      Ypd, Wpair + kNPairs * 192, seg, idx_j, Z, emb, x1,
      W1 + kF * kF, W2 + kF * kF, W3 + kF * kF,
      Wg + kF * 192, bg + 192, out);
}